// Round 28
// baseline (183.173 us; speedup 1.0000x reference)
//
#include <hip/hip_runtime.h>

typedef float4 f4;
#define DEV static __device__ __forceinline__

constexpr int Ln = 1024;
constexpr float EPSn = 1e-9f;

typedef __attribute__((ext_vector_type(8))) short short8;
typedef __attribute__((ext_vector_type(16))) float f32x16;
typedef __attribute__((ext_vector_type(4))) unsigned int u32x4;

// ---------- ws layout (float offsets) ----------
constexpr size_t OFF_T64 = 0;                  // t64 (read-only after patch)
constexpr size_t OFF_H   = 1048576;            // h
constexpr size_t OFF_Q   = 2097152;            // q -> v64
constexpr size_t OFF_K   = 3145728;            // k -> qvb/kvb/pasum
constexpr size_t OFF_V   = 4194304;            // v -> rbf pacc chunk0
constexpr size_t OFF_AO  = 5242880;            // attnout -> rbf pacc chunk1
constexpr size_t OFF_TR  = 6291456;            // cwT (24576)
constexpr size_t OFF_WQT = OFF_TR + 24576;
constexpr size_t OFF_WKT = OFF_WQT + 4096;
constexpr size_t OFF_WVT = OFF_WKT + 4096;
constexpr size_t OFF_WOT = OFF_WVT + 4096;
constexpr size_t OFF_U   = OFF_WOT + 4096;     // (unused)
constexpr size_t OFF_W2P = OFF_U + 1024;       // w2p[u4][o][4]
constexpr size_t OFF_W1P = OFF_W2P + 16384;    // w1p[d4][u][4]
constexpr size_t OFF_UT  = OFF_W1P + 16384;    // UreT/UimT per branch

DEV float red16(float v) {
  v += __shfl_xor(v, 1); v += __shfl_xor(v, 2);
  v += __shfl_xor(v, 4); v += __shfl_xor(v, 8);
  return v;
}

DEV unsigned int pk_bf16(float lo, float hi) {
  unsigned int r;
  asm("v_cvt_pk_bf16_f32 %0, %1, %2" : "=v"(r) : "v"(lo), "v"(hi));
  return r;
}

DEV float fast_exp2(float x) {
#if __has_builtin(__builtin_amdgcn_exp2f)
  return __builtin_amdgcn_exp2f(x);
#else
  return __expf(x * 0.6931471805599453f);
#endif
}

DEV void cmulc(float ar, float ai, float br, float bi, float& cr, float& ci) {
  cr = ar * br - ai * bi; ci = ar * bi + ai * br;
}
DEV void mat2mul(const float* A, const float* B, float* C) { // 2x2 complex, C=A*B
  for (int i = 0; i < 2; ++i)
    for (int j = 0; j < 2; ++j) {
      float sr = 0.f, si = 0.f;
      for (int kk = 0; kk < 2; ++kk) {
        float pr, pi;
        cmulc(A[(i * 2 + kk) * 2], A[(i * 2 + kk) * 2 + 1],
              B[(kk * 2 + j) * 2], B[(kk * 2 + j) * 2 + 1], pr, pi);
        sr += pr; si += pi;
      }
      C[(i * 2 + j) * 2] = sr; C[(i * 2 + j) * 2 + 1] = si;
    }
}

// === fused prep: blocks 0-287 weight transposes; blocks 288-299 gate+unitary ===
__global__ __launch_bounds__(256) void prep_all_kernel(
    const float* __restrict__ conv_w, const float* __restrict__ wq,
    const float* __restrict__ wk, const float* __restrict__ wv,
    const float* __restrict__ wo, const float* __restrict__ w1,
    const float* __restrict__ w2,
    const float* __restrict__ enc_w, const float* __restrict__ q_w,
    const float* __restrict__ k_w, const float* __restrict__ v_w,
    const float* __restrict__ mq, const float* __restrict__ mk,
    const float* __restrict__ mv, float* __restrict__ ws) {
  __shared__ float Ulds[288];
  int bx = blockIdx.x;
  int tid = threadIdx.x;
  if (bx < 288) {
    int g = bx * 256 + tid;
    if (g < 24576) {
      int kk = g / 384, o = g % 384;
      ws[OFF_TR + g] = conv_w[o * 64 + kk];
    } else if (g < 40960) {
      int i = g - 24576;
      int m = i >> 12;
      int r = i & 4095;
      int d = r >> 6, o = r & 63;
      const float* src = m == 0 ? wq : m == 1 ? wk : m == 2 ? wv : wo;
      ws[OFF_WQT + i] = src[o * 64 + d];
    } else if (g < 57344) {
      int i = g - 40960;            // w2p[u4][o][j] = w2[o][u4*4+j]
      int u4 = i >> 8, r = i & 255, o = r >> 2, j = r & 3;
      ws[OFF_W2P + i] = w2[o * 256 + u4 * 4 + j];
    } else if (g < 73728) {
      int i = g - 57344;            // w1p[d4][u][j] = w1[u][d4*4+j]
      int d4 = i >> 10, r = i & 1023, u = r >> 2, j = r & 3;
      ws[OFF_W1P + i] = w1[u * 64 + d4 * 4 + j];
    }
    return;
  }
  // ---- ubuild blocks ----
  int ub = bx - 288;                // 0..11
  int branch = ub >> 2, quad = ub & 3;
  const float* bw = branch == 0 ? q_w : branch == 1 ? k_w : v_w;
  const float* mw = branch == 0 ? mq : branch == 1 ? mk : mv;
  if (tid < 36) {
    int blk = tid / 6, wire = tid % 6;
    auto W = [&](int l, int t) -> float {
      if (l <= 1) return enc_w[(l * 6 + wire) * 3 + t];
      if (l <= 3) return bw[((l - 2) * 6 + wire) * 3 + t];
      return mw[wire * 3 + t];
    };
    auto mk_rx = [](float th, float* M) {
      float c = cosf(0.5f * th), s = sinf(0.5f * th);
      M[0] = c; M[1] = 0; M[2] = 0; M[3] = -s; M[4] = 0; M[5] = -s; M[6] = c; M[7] = 0;
    };
    auto mk_ry = [](float th, float* M) {
      float c = cosf(0.5f * th), s = sinf(0.5f * th);
      M[0] = c; M[1] = 0; M[2] = -s; M[3] = 0; M[4] = s; M[5] = 0; M[6] = c; M[7] = 0;
    };
    float R[8];
    if (blk == 0) {           // RY1(W0)*RX(W0)
      float Am[8], Bx[8];
      mk_ry(W(0, 1), Am); mk_rx(W(0, 0), Bx);
      mat2mul(Am, Bx, R);
    } else if (blk <= 4) {    // RY1(Wb)*RX(Wb)*RY2(W{b-1})
      float Am[8], Bx[8], C[8], T[8];
      mk_ry(W(blk, 1), Am); mk_rx(W(blk, 0), Bx); mk_ry(W(blk - 1, 2), C);
      mat2mul(Bx, C, T); mat2mul(Am, T, R);
    } else {                  // RY2(W4)
      mk_ry(W(4, 2), R);
    }
#pragma unroll
    for (int t = 0; t < 8; ++t) Ulds[(blk * 6 + wire) * 8 + t] = R[t];
  }
  __syncthreads();
  if (tid >= 64) return;
  int s = tid & 3;
  int lane = tid;
  int c = quad * 16 + (tid >> 2);
  bool bit1 = (s & 2) != 0;
  bool bit0 = (s & 1) != 0;
  float re[16], im[16];
#pragma unroll
  for (int i = 0; i < 16; ++i) { re[i] = (s * 16 + i == c) ? 1.f : 0.f; im[i] = 0.f; }
#pragma unroll 1
  for (int blk = 0; blk < 6; ++blk) {
    const float* Uw = Ulds + blk * 48;
    {
      const float* M = Uw;
      float cAr = bit1 ? M[6] : M[0], cAi = bit1 ? M[7] : M[1];
      float cBr = bit1 ? M[4] : M[2], cBi = bit1 ? M[5] : M[3];
#pragma unroll
      for (int i = 0; i < 16; ++i) {
        float pr = __shfl_xor(re[i], 2);
        float pi = __shfl_xor(im[i], 2);
        float nr = cAr * re[i] - cAi * im[i] + cBr * pr - cBi * pi;
        float ni = cAr * im[i] + cAi * re[i] + cBr * pi + cBi * pr;
        re[i] = nr; im[i] = ni;
      }
    }
    {
      const float* M = Uw + 8;
      float cAr = bit0 ? M[6] : M[0], cAi = bit0 ? M[7] : M[1];
      float cBr = bit0 ? M[4] : M[2], cBi = bit0 ? M[5] : M[3];
#pragma unroll
      for (int i = 0; i < 16; ++i) {
        float pr = __shfl_xor(re[i], 1);
        float pi = __shfl_xor(im[i], 1);
        float nr = cAr * re[i] - cAi * im[i] + cBr * pr - cBi * pi;
        float ni = cAr * im[i] + cAi * re[i] + cBr * pi + cBi * pr;
        re[i] = nr; im[i] = ni;
      }
    }
#pragma unroll
    for (int w = 2; w < 6; ++w) {
      const float* M = Uw + w * 8;
      const float m0 = M[0], m1 = M[1], m2 = M[2], m3 = M[3];
      const float m4 = M[4], m5 = M[5], m6 = M[6], m7 = M[7];
      const int mm = 8 >> (w - 2);
#pragma unroll
      for (int i = 0; i < 16; ++i) {
        if (i & mm) continue;
        int i1 = i | mm;
        float ar = re[i], ai = im[i], br = re[i1], bi = im[i1];
        re[i]  = m0 * ar - m1 * ai + m2 * br - m3 * bi;
        im[i]  = m0 * ai + m1 * ar + m2 * bi + m3 * br;
        re[i1] = m4 * ar - m5 * ai + m6 * br - m7 * bi;
        im[i1] = m4 * ai + m5 * ar + m6 * bi + m7 * br;
      }
    }
    if (blk < 5) {
      int sl = (lane & ~3) | (bit1 ? (s ^ 1) : s);
      float tr[16], ti[16];
#pragma unroll
      for (int i = 0; i < 16; ++i) {
        tr[i] = __shfl(re[i], sl);
        ti[i] = __shfl(im[i], sl);
      }
#pragma unroll
      for (int i = 0; i < 16; ++i) {
        int j = i;
        if (j & 2) j ^= 1;
        if (j & 4) j ^= 2;
        if (j & 8) j ^= 4;
        re[i] = bit0 ? tr[j ^ 8] : tr[j];
        im[i] = bit0 ? ti[j ^ 8] : ti[j];
      }
    }
  }
  float* dre = ws + OFF_UT + (size_t)branch * 8192 + c * 64 + s * 16;
  float* dim = dre + 4096;
#pragma unroll
  for (int i = 0; i < 16; i += 4) {
    f4 r4 = {re[i], re[i + 1], re[i + 2], re[i + 3]};
    f4 i4 = {im[i], im[i + 1], im[i + 2], im[i + 3]};
    *(f4*)(dre + i) = r4;
    *(f4*)(dim + i) = i4;
  }
}

// == fused patch embed + LN1/QKV: 512 blocks (256 token-tiles x 2 halves) ==
// half 0: t384 cols 0-191, t64 store, Q; half 1: t384 cols 192-383, K then V.
// hinA[64][65]: persistent LN output, 65-pad => conflict-free broadcast reads.
__global__ __launch_bounds__(256) void patchqkv_kernel(const float* __restrict__ x,
    const float* __restrict__ cwT, const float* __restrict__ conv_b,
    const float* __restrict__ wqT, const float* __restrict__ wkT,
    const float* __restrict__ wvT,
    const float* __restrict__ g1, const float* __restrict__ b1,
    float* __restrict__ out, float* __restrict__ t64,
    float* __restrict__ qo, float* __restrict__ ko, float* __restrict__ vo) {
  __shared__ float A[64][73];    // [k][tok]
  __shared__ float scl[64];
  __shared__ float hinA[64][65]; // LN1 output for all 64 tokens
  __shared__ float wS[4096];     // one 64x64 weight matrix at a time
  int tid = threadIdx.x;
  int tb = blockIdx.x >> 1;
  int half = blockIdx.x & 1;
  int b = tb >> 4;
  int l0 = (tb & 15) << 6;
  {
    const float* w0p = (half == 0) ? wqT : wkT;
#pragma unroll
    for (int p = 0; p < 16; ++p) wS[p * 256 + tid] = w0p[p * 256 + tid];
  }
  int seg = tid & 15;
  int c = seg >> 2, ph = seg & 3;
#pragma unroll
  for (int r = 0; r < 4; ++r) {
    int tok = (tid >> 4) + (r << 4);
    int l = l0 + tok, hp = l >> 5, wp = l & 31;
    f4 v4 = *(const f4*)(x + (size_t)((b * 4 + c) * 128 + hp * 4 + ph) * 128 + wp * 4);
    A[seg * 4 + 0][tok] = v4.x;
    A[seg * 4 + 1][tok] = v4.y;
    A[seg * 4 + 2][tok] = v4.z;
    A[seg * 4 + 3][tok] = v4.w;
  }
  __syncthreads();
  if (tid < 64) {
    float ss = 0.f;
#pragma unroll
    for (int kk = 0; kk < 64; ++kk) { float vv = A[kk][tid]; ss += vv * vv; }
    scl[tid] = 1.0f / (sqrtf(ss) + EPSn);
  }
  __syncthreads();
  int t0 = tb << 6;
  if (half == 0) {
#pragma unroll
    for (int i = 0; i < 16; ++i) {
      int idx = tid + (i << 8);
      int tok = idx >> 6, kk = idx & 63;
      t64[(size_t)(t0 + tok) * 64 + kk] = A[kk][tok] * scl[tok];
    }
  }
  // ---- t384 GEMM 64x64 @ 64x192 (this half's cols), cwT staged-transpose ----
  {
    int tg = tid >> 4;            // 16 token-groups of 4
    int on = (tid & 15) + half * 16;  // out cols on*12..+12
    float acc[4][12];
#pragma unroll
    for (int i = 0; i < 4; ++i)
#pragma unroll
      for (int jj = 0; jj < 12; ++jj) acc[i][jj] = 0.f;
    for (int kk = 0; kk < 64; ++kk) {
      float a[4];
#pragma unroll
      for (int i = 0; i < 4; ++i) a[i] = A[kk][tg * 4 + i];
      f4 w0 = *(const f4*)(cwT + kk * 384 + on * 12);
      f4 w1 = *(const f4*)(cwT + kk * 384 + on * 12 + 4);
      f4 w2 = *(const f4*)(cwT + kk * 384 + on * 12 + 8);
      float wv_[12] = {w0.x, w0.y, w0.z, w0.w, w1.x, w1.y, w1.z, w1.w,
                       w2.x, w2.y, w2.z, w2.w};
#pragma unroll
      for (int i = 0; i < 4; ++i)
#pragma unroll
        for (int jj = 0; jj < 12; ++jj) acc[i][jj] += a[i] * wv_[jj];
    }
#pragma unroll
    for (int i = 0; i < 4; ++i) {
      int tok = tg * 4 + i;
      size_t basep = (size_t)(t0 + tok) * 448 + on * 12;
#pragma unroll
      for (int jj = 0; jj < 12; ++jj)
        out[basep + jj] = acc[i][jj] + conv_b[on * 12 + jj];
    }
  }
  // ---- LN1 for all 64 tokens (identical arithmetic to before) ----
  int tt = tid >> 4, part = tid & 15;
#pragma unroll
  for (int pass = 0; pass < 4; ++pass) {
    int tokL = pass * 16 + tt;
    float sclv = scl[tokL];
    float e0 = A[part * 4 + 0][tokL] * sclv;
    float e1 = A[part * 4 + 1][tokL] * sclv;
    float e2 = A[part * 4 + 2][tokL] * sclv;
    float e3 = A[part * 4 + 3][tokL] * sclv;
    float mean = red16(e0 + e1 + e2 + e3) * 0.015625f;
    float d0 = e0 - mean, d1 = e1 - mean, d2 = e2 - mean, d3 = e3 - mean;
    float var = red16(d0 * d0 + d1 * d1 + d2 * d2 + d3 * d3) * 0.015625f;
    float rs = rsqrtf(var + 1e-5f);
    f4 g4 = *(const f4*)(g1 + part * 4);
    f4 b4 = *(const f4*)(b1 + part * 4);
    f4 hh;
    hh.x = d0 * rs * g4.x + b4.x; hh.y = d1 * rs * g4.y + b4.y;
    hh.z = d2 * rs * g4.z + b4.z; hh.w = d3 * rs * g4.w + b4.w;
    *(f4*)&hinA[tokL][part * 4] = hh;
  }
  __syncthreads();
  // ---- GEMM 1: Q (half 0) / K (half 1) for all 64 tokens ----
  {
    float* dst = (half == 0) ? qo : ko;
#pragma unroll 1
    for (int pass = 0; pass < 4; ++pass) {
      int tokL = pass * 16 + tt;
      int t = t0 + tokL;
      float a0 = 0, a1 = 0, a2 = 0, a3 = 0;
      for (int d = 0; d < 64; ++d) {
        float hd = hinA[tokL][d];
        f4 w4 = *(const f4*)&wS[d * 64 + part * 4];
        a0 += hd * w4.x; a1 += hd * w4.y; a2 += hd * w4.z; a3 += hd * w4.w;
      }
      f4 r = {a0, a1, a2, a3};
      *(f4*)(dst + (size_t)t * 64 + part * 4) = r;
    }
  }
  // ---- half 1: restage wvT, GEMM 2: V ----
  if (half == 1) {
    __syncthreads();
#pragma unroll
    for (int p = 0; p < 16; ++p) wS[p * 256 + tid] = wvT[p * 256 + tid];
    __syncthreads();
#pragma unroll 1
    for (int pass = 0; pass < 4; ++pass) {
      int tokL = pass * 16 + tt;
      int t = t0 + tokL;
      float a0 = 0, a1 = 0, a2 = 0, a3 = 0;
      for (int d = 0; d < 64; ++d) {
        float hd = hinA[tokL][d];
        f4 w4 = *(const f4*)&wS[d * 64 + part * 4];
        a0 += hd * w4.x; a1 += hd * w4.y; a2 += hd * w4.z; a3 += hd * w4.w;
      }
      f4 r = {a0, a1, a2, a3};
      *(f4*)(vo + (size_t)t * 64 + part * 4) = r;
    }
  }
}

// ===== classic MHSA: bf16 MFMA flash attention (b128-V, exp2, permlane swap) =====
__global__ __launch_bounds__(256) void attn_kernel(const float* __restrict__ qg,
    const float* __restrict__ kg, const float* __restrict__ vg, float* __restrict__ ao) {
  __shared__ __align__(16) unsigned short Klds[Ln][8];    // 16 KB bf16 (pre-scaled)
  __shared__ __align__(16) unsigned short Vt[10][1032];   // 20.2 KB bf16, d-major (+pad)
  __shared__ __align__(16) unsigned short Qlds[128][8];   // 2 KB bf16
  int bh = blockIdx.x;
  int b = bh >> 3, hh = bh & 7;
  int tid = threadIdx.x;
  int qbase = (blockIdx.y << 7);    // 128 queries per block
  const float* kb = kg + (size_t)(b * Ln) * 64 + hh * 8;
  const float* vb = vg + (size_t)(b * Ln) * 64 + hh * 8;
  const float* qb = qg + (size_t)(b * Ln + qbase) * 64 + hh * 8;
  const float SC = 0.51006944f;     // (1/sqrt(8)) * log2(e), folded into K
#pragma unroll
  for (int p = 0; p < 8; ++p) {
    int e4 = p * 256 + tid;         // 0..2047
    int j = e4 >> 1, part = e4 & 1;
    f4 kv = *(const f4*)(kb + (size_t)j * 64 + part * 4);
    *(uint2*)&Klds[j][part * 4] =
        make_uint2(pk_bf16(kv.x * SC, kv.y * SC), pk_bf16(kv.z * SC, kv.w * SC));
    f4 vv = *(const f4*)(vb + (size_t)j * 64 + part * 4);
    unsigned int u01 = pk_bf16(vv.x, vv.y), u23 = pk_bf16(vv.z, vv.w);
    int d0 = part * 4;
    Vt[d0 + 0][j] = (unsigned short)u01;
    Vt[d0 + 1][j] = (unsigned short)(u01 >> 16);
    Vt[d0 + 2][j] = (unsigned short)u23;
    Vt[d0 + 3][j] = (unsigned short)(u23 >> 16);
  }
#pragma unroll
  for (int p = 0; p < 4; ++p) {
    int j = p * 256 + tid;
    Vt[8][j] = 0x3F80;              // ones row (denominator)
    Vt[9][j] = 0;                   // zero row (clamp target)
  }
  {
    int j = tid >> 1, part = tid & 1;
    f4 qv = *(const f4*)(qb + (size_t)j * 64 + part * 4);
    *(uint2*)&Qlds[j][part * 4] = make_uint2(pk_bf16(qv.x, qv.y), pk_bf16(qv.z, qv.w));
  }
  __syncthreads();

  int l = tid & 63, w = tid >> 6;
  int lq = l & 31;
  bool lo = l < 32;
  const short8 zero8 = {0, 0, 0, 0, 0, 0, 0, 0};
  short8 qf = *(const short8*)&Qlds[w * 32 + lq][0];
  qf = lo ? qf : zero8;
  int d = lq;
  int dc = d > 9 ? 9 : d;
  int vrow0 = (l >> 5) * 8;
  f32x16 acc = {};
  const f32x16 fz = {};
  for (int t = 0; t < 32; ++t) {
    short8 kf = *(const short8*)&Klds[t * 32 + lq][0];
    kf = lo ? kf : zero8;
    f32x16 s = __builtin_amdgcn_mfma_f32_32x32x16_bf16(kf, qf, fz, 0, 0, 0);
    float p[16];
#pragma unroll
    for (int r = 0; r < 16; ++r) p[r] = fast_exp2(s[r]);   // K pre-scaled: p = 2^s
    unsigned int c0 = pk_bf16(p[0], p[1]),  c1 = pk_bf16(p[2], p[3]);
    unsigned int c2 = pk_bf16(p[4], p[5]),  c3 = pk_bf16(p[6], p[7]);
    unsigned int c4 = pk_bf16(p[8], p[9]),  c5 = pk_bf16(p[10], p[11]);
    unsigned int c6 = pk_bf16(p[12], p[13]), c7 = pk_bf16(p[14], p[15]);
    // cross-half exchange via permlane32_swap: X=[a.lo|b.lo], Y=[a.hi|b.hi]
    unsigned int x0 = c0, y0 = c2;
    asm("v_permlane32_swap_b32 %0, %1" : "+v"(x0), "+v"(y0));
    unsigned int x1 = c1, y1 = c3;
    asm("v_permlane32_swap_b32 %0, %1" : "+v"(x1), "+v"(y1));
    unsigned int x4 = c4, y4 = c6;
    asm("v_permlane32_swap_b32 %0, %1" : "+v"(x4), "+v"(y4));
    unsigned int x5 = c5, y5 = c7;
    asm("v_permlane32_swap_b32 %0, %1" : "+v"(x5), "+v"(y5));
    union { u32x4 u; short8 s8; } B0, B1;
    B0.u = (u32x4){x0, x1, y0, y1};   // lo:{c0,c1,pc0,pc1} hi:{pc2,pc3,c2,c3}
    B1.u = (u32x4){x4, x5, y4, y5};   // lo:{c4,c5,pc4,pc5} hi:{pc6,pc7,c6,c7}
    int jb = t * 32 + vrow0;
    short8 av0 = *(const short8*)&Vt[dc][jb];        // ds_read_b128 (aligned)
    short8 av1 = *(const short8*)&Vt[dc][jb + 16];   // ds_read_b128
    acc = __builtin_amdgcn_mfma_f32_32x32x16_bf16(av0, B0.s8, acc, 0, 0, 0);
    acc = __builtin_amdgcn_mfma_f32_32x32x16_bf16(av1, B1.s8, acc, 0, 0, 0);
  }
  float ssum = __shfl(acc[4], lq);
  float inv = 1.0f / ssum;
  f4 o = {acc[0] * inv, acc[1] * inv, acc[2] * inv, acc[3] * inv};
  float* dst = ao + (size_t)(b * Ln + qbase + w * 32 + lq) * 64 + hh * 8 + (lo ? 0 : 4);
  *(f4*)dst = o;
}

// ========= out-proj residual + LN2 + normalize (st); woT staged in LDS =========
__global__ __launch_bounds__(256) void proj_st_kernel(float* __restrict__ t64st,
    const float* __restrict__ ao, const float* __restrict__ woT, const float* __restrict__ bo,
    const float* __restrict__ g2, const float* __restrict__ b2, const float* __restrict__ iscale,
    float* __restrict__ hB) {
  __shared__ float woS[4096];   // 16 KB
  __shared__ float aos[16][64];
  int tid = threadIdx.x;
#pragma unroll
  for (int p = 0; p < 16; ++p) {
    int idx = p * 256 + tid;
    woS[idx] = woT[idx];
  }
  int t0 = blockIdx.x << 4;
  int tt = tid >> 4, part = tid & 15;
  int t = t0 + tt;
  *(f4*)&aos[tt][part * 4] = *(const f4*)(ao + (size_t)t * 64 + part * 4);
  __syncthreads();
  f4 acc;
  acc.x = bo[part * 4 + 0]; acc.y = bo[part * 4 + 1];
  acc.z = bo[part * 4 + 2]; acc.w = bo[part * 4 + 3];
  for (int d = 0; d < 64; ++d) {
    float ad = aos[tt][d];
    f4 w4 = *(const f4*)&woS[d * 64 + part * 4];
    acc.x += ad * w4.x; acc.y += ad * w4.y; acc.z += ad * w4.z; acc.w += ad * w4.w;
  }
  f4 tv = *(const f4*)(t64st + (size_t)t * 64 + part * 4);
  f4 hv = {tv.x + acc.x, tv.y + acc.y, tv.z + acc.z, tv.w + acc.w};
  *(f4*)(hB + (size_t)t * 64 + part * 4) = hv;
  float mean = red16(hv.x + hv.y + hv.z + hv.w) * 0.015625f;
  float d0 = hv.x - mean, d1 = hv.y - mean, d2 = hv.z - mean, d3 = hv.w - mean;
  float var = red16(d0 * d0 + d1 * d1 + d2 * d2 + d3 * d3) * 0.015625f;
  float rs = rsqrtf(var + 1e-5f);
  f4 g4 = *(const f4*)(g2 + part * 4);
  f4 b4 = *(const f4*)(b2 + part * 4);
  f4 is4 = *(const f4*)(iscale + part * 4);
  float x0 = (d0 * rs * g4.x + b4.x) * is4.x;
  float x1 = (d1 * rs * g4.y + b4.y) * is4.y;
  float x2 = (d2 * rs * g4.z + b4.z) * is4.z;
  float x3 = (d3 * rs * g4.w + b4.w) * is4.w;
  float nrm = sqrtf(red16(x0 * x0 + x1 * x1 + x2 * x2 + x3 * x3));
  float rn = 1.0f / (nrm + EPSn);
  f4 stv = {x0 * rn, x1 * rn, x2 * rn, x3 * rn};
  *(f4*)(t64st + (size_t)t * 64 + part * 4) = stv;
}

// ======== quantum: psi_out = st @ U_total^T as fp32 LDS GEMM + epilogue ========
__global__ __launch_bounds__(256) void quantum_kernel(const float* __restrict__ st,
    const float* __restrict__ ut,
    const float* __restrict__ qproj_w, const float* __restrict__ qproj_b,
    const float* __restrict__ kproj_w, const float* __restrict__ kproj_b,
    const float* __restrict__ qkg, const float* __restrict__ qkb,
    float* __restrict__ qvb, float* __restrict__ kvb, float* __restrict__ v64) {
  __shared__ float smem[12288];     // sts[4096] | ure[4096] | uim[4096]; plds aliases front
  int tid = threadIdx.x;
  int branch = blockIdx.y;
  int t0 = blockIdx.x << 6;         // 64 tokens/block
  const float* ub = ut + (size_t)branch * 8192;
#pragma unroll
  for (int p = 0; p < 16; ++p) {
    int idx = p * 256 + tid;        // 0..4095
    smem[idx] = st[(size_t)t0 * 64 + idx];
    smem[4096 + idx] = ub[idx];
    smem[8192 + idx] = ub[4096 + idx];
  }
  __syncthreads();
  int o = tid & 63, tg = tid >> 6;
  float accre[16], accim[16];
#pragma unroll
  for (int i = 0; i < 16; ++i) { accre[i] = 0.f; accim[i] = 0.f; }
  for (int k4 = 0; k4 < 16; ++k4) {
    float ur[4], ui[4];
#pragma unroll
    for (int j = 0; j < 4; ++j) {
      ur[j] = smem[4096 + (k4 * 4 + j) * 64 + o];   // stride-1 lanes: conflict-free
      ui[j] = smem[8192 + (k4 * 4 + j) * 64 + o];
    }
#pragma unroll
    for (int tt = 0; tt < 16; ++tt) {
      f4 a = *(const f4*)&smem[(tg * 16 + tt) * 64 + k4 * 4];  // broadcast
      accre[tt] += a.x * ur[0] + a.y * ur[1] + a.z * ur[2] + a.w * ur[3];
      accim[tt] += a.x * ui[0] + a.y * ui[1] + a.z * ui[2] + a.w * ui[3];
    }
  }
  __syncthreads();                  // everyone done reading sts/U
#pragma unroll
  for (int tt = 0; tt < 16; ++tt) {
    int t = tg * 16 + tt;
    smem[t * 65 + o] = accre[tt] * accre[tt] + accim[tt] * accim[tt];  // plds (65-pad)
  }
  __syncthreads();
  // ---- remap epilogue: thread (token, quarter s) ----
  int s = tid & 3;
  int tokL = tid >> 2;              // 0..63
  int token = t0 + tokL;
  bool bit1 = (s & 2) != 0;
  bool bit0 = (s & 1) != 0;
  float p[16];
#pragma unroll
  for (int i = 0; i < 16; ++i) p[i] = smem[tokL * 65 + s * 16 + i];
  float lsum = 0.f;
#pragma unroll
  for (int i = 0; i < 16; ++i) lsum += p[i];
  if (branch == 2) {
    float tot = lsum;
    tot += __shfl_xor(tot, 1);
    tot += __shfl_xor(tot, 2);
    float rn = 1.0f / (tot + EPSn);
    float* dst = v64 + (size_t)token * 64 + s * 16;
#pragma unroll
    for (int i = 0; i < 16; i += 4) {
      f4 o4 = {p[i] * rn, p[i + 1] * rn, p[i + 2] * rn, p[i + 3] * rn};
      *(f4*)(dst + i) = o4;
    }
  } else {
    float lz[4] = {0.f, 0.f, 0.f, 0.f};
#pragma unroll
    for (int i = 0; i < 16; ++i) {
      lz[0] += (i & 8) ? -p[i] : p[i];
      lz[1] += (i & 4) ? -p[i] : p[i];
      lz[2] += (i & 2) ? -p[i] : p[i];
      lz[3] += (i & 1) ? -p[i] : p[i];
    }
    float z[6];
    float u0 = bit1 ? -lsum : lsum;
    u0 += __shfl_xor(u0, 1); u0 += __shfl_xor(u0, 2); z[0] = u0;
    float u1 = bit0 ? -lsum : lsum;
    u1 += __shfl_xor(u1, 1); u1 += __shfl_xor(u1, 2); z[1] = u1;
#pragma unroll
    for (int q = 0; q < 4; ++q) {
      float v = lz[q];
      v += __shfl_xor(v, 1); v += __shfl_xor(v, 2);
      z[2 + q] = v;
    }
    const float* pw = branch == 0 ? qproj_w : kproj_w;
    const float* pb = branch == 0 ? qproj_b : kproj_b;
    float pr4[4];
#pragma unroll
    for (int jj = 0; jj < 4; ++jj) {
      float a = pb[jj];
#pragma unroll
      for (int qq = 0; qq < 6; ++qq) a += z[qq] * pw[jj * 6 + qq];
      pr4[jj] = a;
    }
    float mean = (pr4[0] + pr4[1] + pr4[2] + pr4[3]) * 0.25f;
    float var = 0.f;
#pragma unroll
    for (int jj = 0; jj < 4; ++jj) { float dd = pr4[jj] - mean; var += dd * dd; }
    var *= 0.25f;
    float rs = rsqrtf(var + 1e-5f);
    if (s == 0) {
      f4 o4;
      o4.x = (pr4[0] - mean) * rs * qkg[0] + qkb[0];
      o4.y = (pr4[1] - mean) * rs * qkg[1] + qkb[1];
      o4.z = (pr4[2] - mean) * rs * qkg[2] + qkb[2];
      o4.w = (pr4[3] - mean) * rs * qkg[3] + qkb[3];
      *(f4*)((branch == 0 ? qvb : kvb) + (size_t)token * 4) = o4;
    }
  }
}

// ==== RBF kernel attention: bf16 MFMA flash (transposed V, exp2-folded) ====
__global__ __launch_bounds__(256) void rbf_kernel(const float* __restrict__ qvb,
    const float* __restrict__ kvb, const float* __restrict__ v64,
    const float* __restrict__ raw_tau, float* __restrict__ pacc, float* __restrict__ pasum) {
  __shared__ __align__(16) unsigned short Vt[64][520];     // 65 KB bf16, d-major (+pad)
  __shared__ __align__(16) unsigned short kvbs[512][8];    // 8 KB bf16 (pre-scaled, 4+4 zero)
  __shared__ float kks[512];                               // (k.k)/tau * log2e
  int tid = threadIdx.x;
  int q0 = blockIdx.x << 7;          // 128 queries/block (global token index)
  int b = q0 >> 10;
  int kc = blockIdx.y;               // key chunk (512 each)
  float tau = log1pf(__expf(raw_tau[0]));
  const float L2E = 1.4426950408889634f;
  float sck = 2.0f * L2E / tau;      // fold into staged k: s' = (q.k)*sck
  int kbase = b * Ln + (kc << 9);
#pragma unroll
  for (int p = 0; p < 2; ++p) {
    int j = p * 256 + tid;
    f4 kv4 = *(const f4*)(kvb + (size_t)(kbase + j) * 4);
    kks[j] = (kv4.x * kv4.x + kv4.y * kv4.y + kv4.z * kv4.z + kv4.w * kv4.w) * (L2E / tau);
    *(uint4*)&kvbs[j][0] =
        make_uint4(pk_bf16(kv4.x * sck, kv4.y * sck), pk_bf16(kv4.z * sck, kv4.w * sck), 0u, 0u);
  }
#pragma unroll
  for (int it = 0; it < 32; ++it) {
    int idx = it * 256 + tid;        // f4 index over 512*16
    int row = idx >> 4, c4 = idx & 15;
    f4 vv = *(const f4*)(v64 + (size_t)(kbase + row) * 64 + c4 * 4);
    unsigned int u01 = pk_bf16(vv.x, vv.y), u23 = pk_bf16(vv.z, vv.w);
    int d0 = c4 * 4;
    Vt[d0 + 0][row] = (unsigned short)u01;
    Vt[d0 + 1][row] = (unsigned short)(u01 >> 16);
    Vt[d0 + 2][row] = (unsigned short)u23;
    Vt[d0 + 3][row] = (unsigned short)(u23 >> 16);
  }
  __syncthreads();

  int l = tid & 63, w = tid >> 6;
  int lq = l & 31;
  bool lo = l < 32;
  bool hi = !lo;
  const short8 zero8 = {0, 0, 0, 0, 0, 0, 0, 0};
  int qtok = q0 + w * 32 + lq;
  f4 qv4 = *(const f4*)(qvb + (size_t)qtok * 4);
  union { u32x4 u; short8 s8; } Qf;
  Qf.u = (u32x4){pk_bf16(qv4.x, qv4.y), pk_bf16(qv4.z, qv4.w), 0u, 0u};
  short8 qf = lo ? Qf.s8 : zero8;
  int vrow0 = (l >> 5) * 8;
  int dbase = hi ? 4 : 0;
  f32x16 acc0 = {}, acc1 = {};
  const f32x16 fz = {};
  float dsum = 0.f;
  for (int t = 0; t < 16; ++t) {     // 16 tiles x 32 keys
    short8 kf = lo ? *(const short8*)&kvbs[t * 32 + lq][0] : zero8;
    f32x16 s = __builtin_amdgcn_mfma_f32_32x32x16_bf16(kf, qf, fz, 0, 0, 0);
    int rowbase = t * 32 + dbase;
    float p[16];
#pragma unroll
    for (int r = 0; r < 16; ++r) {
      float kkv = kks[rowbase + (r & 3) + 8 * (r >> 2)];
      p[r] = fast_exp2(s[r] - kkv);
      dsum += p[r];
    }
    unsigned int c0 = pk_bf16(p[0], p[1]),  c1 = pk_bf16(p[2], p[3]);
    unsigned int c2 = pk_bf16(p[4], p[5]),  c3 = pk_bf16(p[6], p[7]);
    unsigned int c4 = pk_bf16(p[8], p[9]),  c5 = pk_bf16(p[10], p[11]);
    unsigned int c6 = pk_bf16(p[12], p[13]), c7 = pk_bf16(p[14], p[15]);
    unsigned int x0 = c0, y0 = c2;
    asm("v_permlane32_swap_b32 %0, %1" : "+v"(x0), "+v"(y0));
    unsigned int x1 = c1, y1 = c3;
    asm("v_permlane32_swap_b32 %0, %1" : "+v"(x1), "+v"(y1));
    unsigned int x4 = c4, y4 = c6;
    asm("v_permlane32_swap_b32 %0, %1" : "+v"(x4), "+v"(y4));
    unsigned int x5 = c5, y5 = c7;
    asm("v_permlane32_swap_b32 %0, %1" : "+v"(x5), "+v"(y5));
    union { u32x4 u; short8 s8; } B0, B1;
    B0.u = (u32x4){x0, x1, y0, y1};
    B1.u = (u32x4){x4, x5, y4, y5};
    int jb = t * 32 + vrow0;
    short8 a00 = *(const short8*)&Vt[lq][jb];          // ds_read_b128
    short8 a10 = *(const short8*)&Vt[32 + lq][jb];
    short8 a01 = *(const short8*)&Vt[lq][jb + 16];
    short8 a11 = *(const short8*)&Vt[32 + lq][jb + 16];
    acc0 = __builtin_amdgcn_mfma_f32_32x32x16_bf16(a00, B0.s8, acc0, 0, 0, 0);
    acc1 = __builtin_amdgcn_mfma_f32_32x32x16_bf16(a10, B0.s8, acc1, 0, 0, 0);
    acc0 = __builtin_amdgcn_mfma_f32_32x32x16_bf16(a01, B1.s8, acc0, 0, 0, 0);
    acc1 = __builtin_amdgcn_mfma_f32_32x32x16_bf16(a11, B1.s8, acc1, 0, 0, 0);
  }
  float dtot = dsum + __shfl_xor(dsum, 32);
  if (lo) pasum[(kc << 14) + qtok] = dtot;
  float* pa = pacc + (size_t)kc * 1048576 + (size_t)qtok * 64;
#pragma unroll
  for (int r = 0; r < 16; ++r) {
    int dd = (r & 3) + 8 * (r >> 2) + dbase;
    pa[dd] = acc0[r];
    pa[32 + dd] = acc1[r];
  }
}

// == M0+M1+M2 fused: h += rbf; LN3; hid = gelu(.@w1); out = h + hid@w2 + b2 ==
__global__ __launch_bounds__(256) void m0m1m2_kernel(const float* __restrict__ hB,
    const float* __restrict__ pacc, const float* __restrict__ pasum,
    const float* __restrict__ g3, const float* __restrict__ b3,
    const float* __restrict__ w1p, const float* __restrict__ b1v,
    const float* __restrict__ w2p, const float* __restrict__ b2v,
    float* __restrict__ out) {
  __shared__ float hS[16][64];      // 4 KB: updated h (residual source)
  __shared__ float hmS[16][64];     // 4 KB: LN3 output
  __shared__ float hidS[16][256];   // 16 KB: gelu hidden
  int tid = threadIdx.x;
  int t0 = blockIdx.x << 4;
  {
    int tt = tid >> 4, part = tid & 15;
    int t = t0 + tt;
    f4 hv = *(const f4*)(hB + (size_t)t * 64 + part * 4);
    f4 p0 = *(const f4*)(pacc + (size_t)t * 64 + part * 4);
    f4 p1 = *(const f4*)(pacc + 1048576 + (size_t)t * 64 + part * 4);
    float rden = 1.0f / (pasum[t] + pasum[16384 + t] + EPSn);
    hv.x += (p0.x + p1.x) * rden; hv.y += (p0.y + p1.y) * rden;
    hv.z += (p0.z + p1.z) * rden; hv.w += (p0.w + p1.w) * rden;
    *(f4*)&hS[tt][part * 4] = hv;
    float mean = red16(hv.x + hv.y + hv.z + hv.w) * 0.015625f;
    float d0 = hv.x - mean, d1 = hv.y - mean, d2 = hv.z - mean, d3 = hv.w - mean;
    float var = red16(d0 * d0 + d1 * d1 + d2 * d2 + d3 * d3) * 0.015625f;
    float rs = rsqrtf(var + 1e-5f);
    f4 g4 = *(const f4*)(g3 + part * 4);
    f4 b4 = *(const f4*)(b3 + part * 4);
    f4 o4 = {d0 * rs * g4.x + b4.x, d1 * rs * g4.y + b4.y,
             d2 * rs * g4.z + b4.z, d3 * rs * g4.w + b4.w};
    *(f4*)&hmS[tt][part * 4] = o4;
  }
  __syncthreads();
  // ---- M1: u = tid computes hid[tok][u] for all 16 tokens ----
  {
    int u = tid;
    float wrow[64];
#pragma unroll
    for (int d4 = 0; d4 < 16; ++d4) {
      f4 w4 = *(const f4*)(w1p + d4 * 1024 + u * 4);   // coalesced
      wrow[d4 * 4] = w4.x; wrow[d4 * 4 + 1] = w4.y;
      wrow[d4 * 4 + 2] = w4.z; wrow[d4 * 4 + 3] = w4.w;
    }
    float bias = b1v[u];
    for (int tok = 0; tok < 16; ++tok) {
      const float* hr = hmS[tok];
      float a0 = 0.f, a1 = 0.f, a2 = 0.f, a3 = 0.f;
#pragma unroll
      for (int d = 0; d < 64; d += 4) {
        a0 += hr[d] * wrow[d];
        a1 += hr[d + 1] * wrow[d + 1];
        a2 += hr[d + 2] * wrow[d + 2];
        a3 += hr[d + 3] * wrow[d + 3];
      }
      float a = bias + ((a0 + a1) + (a2 + a3));
      float tz = 0.7978845608028654f * (a + 0.044715f * a * a * a);
      float e = __expf(2.0f * tz);
      float th = 1.0f - 2.0f / (e + 1.0f);
      hidS[tok][u] = 0.5f * a * (1.0f + th);
    }
  }
  __syncthreads();
  // ---- M2: lane owns out col o; 4 token-groups of 4 ----
  int o = tid & 63, tg = tid >> 6;
  f4 acc[4];
#pragma unroll
  for (int tt = 0; tt < 4; ++tt) acc[tt] = {0.f, 0.f, 0.f, 0.f};
#pragma unroll 4
  for (int u4 = 0; u4 < 64; ++u4) {
    f4 wv = *(const f4*)(w2p + u4 * 256 + o * 4);   // coalesced 1KB/wave, L2-hot
#pragma unroll
    for (int tt = 0; tt < 4; ++tt) {
      f4 hv = *(const f4*)&hidS[tg * 4 + tt][u4 * 4];   // broadcast (same addr per wave)
      acc[tt].x += hv.x * wv.x; acc[tt].y += hv.y * wv.y;
      acc[tt].z += hv.z * wv.z; acc[tt].w += hv.w * wv.w;
    }
  }
  float bb = b2v[o];
#pragma unroll
  for (int tt = 0; tt < 4; ++tt) {
    int tok = tg * 4 + tt;
    float r = bb + ((acc[tt].x + acc[tt].y) + (acc[tt].z + acc[tt].w));
    out[(size_t)(t0 + tok) * 448 + 384 + o] = hS[tok][o] + r;
  }
}

// ===================== host =====================
extern "C" void kernel_launch(void* const* d_in, const int* in_sizes, int n_in,
                              void* d_out, int out_size, void* d_ws, size_t ws_size,
                              hipStream_t stream) {
  (void)in_sizes; (void)n_in; (void)out_size; (void)ws_size;
  const float* x       = (const float*)d_in[0];
  const float* conv_w  = (const float*)d_in[1];
  const float* conv_b  = (const float*)d_in[2];
  const float* ln1_g   = (const float*)d_in[3];
  const float* ln1_b   = (const float*)d_in[4];
  const float* wq      = (const float*)d_in[5];
  const float* wk      = (const float*)d_in[6];
  const float* wv      = (const float*)d_in[7];
  const float* wo      = (const float*)d_in[8];
  const float* bo      = (const float*)d_in[9];
  const float* ln2_g   = (const float*)d_in[10];
  const float* ln2_b   = (const float*)d_in[11];
  const float* enc_w   = (const float*)d_in[12];
  const float* q_w     = (const float*)d_in[13];
  const float* k_w     = (const float*)d_in[14];
  const float* v_w     = (const float*)d_in[15];
  const float* mq_w    = (const float*)d_in[16];
  const float* mk_w    = (const float*)d_in[17];
  const float* mv_w    = (const float*)d_in[18];
  const float* qproj_w = (const float*)d_in[19];
  const float* qproj_b = (const float*)d_in[20];
  const float* kproj_w = (const float*)d_in[21];
  const float* kproj_b = (const float*)d_in[22];
  const float* qkln_g  = (const float*)d_in[23];
  const float* qkln_b  = (const float*)d_in[24];
  const float* raw_tau = (const float*)d_in[25];
  const float* iscale  = (const float*)d_in[26];
  const float* ln3_g   = (const float*)d_in[27];
  const float* ln3_b   = (const float*)d_in[28];
  const float* mlp_w1  = (const float*)d_in[29];
  const float* mlp_b1  = (const float*)d_in[30];
  const float* mlp_w2  = (const float*)d_in[31];
  const float* mlp_b2  = (const float*)d_in[32];
  float* out = (float*)d_out;
  float* ws  = (float*)d_ws;

  prep_all_kernel<<<300, 256, 0, stream>>>(conv_w, wq, wk, wv, wo, mlp_w1, mlp_w2,
                                           enc_w, q_w, k_w, v_w, mq_w, mk_w, mv_w, ws);
  patchqkv_kernel<<<512, 256, 0, stream>>>(x, ws + OFF_TR, conv_b,
                                           ws + OFF_WQT, ws + OFF_WKT, ws + OFF_WVT,
                                           ln1_g, ln1_b, out, ws + OFF_T64,
                                           ws + OFF_Q, ws + OFF_K, ws + OFF_V);
  attn_kernel<<<dim3(128, 8), 256, 0, stream>>>(ws + OFF_Q, ws + OFF_K, ws + OFF_V, ws + OFF_AO);
  proj_st_kernel<<<1024, 256, 0, stream>>>(ws + OFF_T64, ws + OFF_AO, ws + OFF_WOT, bo,
                                           ln2_g, ln2_b, iscale, ws + OFF_H);
  quantum_kernel<<<dim3(256, 3), 256, 0, stream>>>(ws + OFF_T64, ws + OFF_UT,
                                                   qproj_w, qproj_b, kproj_w, kproj_b,
                                                   qkln_g, qkln_b,
                                                   ws + OFF_K, ws + OFF_K + 65536, ws + OFF_Q);
  rbf_kernel<<<dim3(128, 2), 256, 0, stream>>>(ws + OFF_K, ws + OFF_K + 65536, ws + OFF_Q,
                                               raw_tau, ws + OFF_V, ws + OFF_K + 131072);
  m0m1m2_kernel<<<1024, 256, 0, stream>>>(ws + OFF_H, ws + OFF_V, ws + OFF_K + 131072,
                                          ln3_g, ln3_b, ws + OFF_W1P, mlp_b1,
                                          ws + OFF_W2P, mlp_b2, out);
}

// Round 29
// 162.090 us; speedup vs baseline: 1.1301x; 1.1301x over previous
//
#include <hip/hip_runtime.h>

typedef float4 f4;
#define DEV static __device__ __forceinline__

constexpr int Ln = 1024;
constexpr float EPSn = 1e-9f;

typedef __attribute__((ext_vector_type(8))) short short8;
typedef __attribute__((ext_vector_type(16))) float f32x16;
typedef __attribute__((ext_vector_type(4))) unsigned int u32x4;

// ---------- ws layout (float offsets) ----------
constexpr size_t OFF_T64 = 0;                  // t64 (read-only after patch)
constexpr size_t OFF_H   = 1048576;            // h
constexpr size_t OFF_Q   = 2097152;            // q -> v64
constexpr size_t OFF_K   = 3145728;            // k -> qvb/kvb/pasum
constexpr size_t OFF_V   = 4194304;            // v -> rbf pacc chunk0
constexpr size_t OFF_AO  = 5242880;            // attnout -> rbf pacc chunk1
constexpr size_t OFF_TR  = 6291456;            // cwT (24576)
constexpr size_t OFF_WQT = OFF_TR + 24576;
constexpr size_t OFF_WKT = OFF_WQT + 4096;
constexpr size_t OFF_WVT = OFF_WKT + 4096;
constexpr size_t OFF_WOT = OFF_WVT + 4096;
constexpr size_t OFF_U   = OFF_WOT + 4096;     // (unused)
constexpr size_t OFF_W2P = OFF_U + 1024;       // w2p[u4][o][4]
constexpr size_t OFF_W1P = OFF_W2P + 16384;    // w1p[d4][u][4]
constexpr size_t OFF_UT  = OFF_W1P + 16384;    // UreT/UimT per branch

DEV float red16(float v) {
  v += __shfl_xor(v, 1); v += __shfl_xor(v, 2);
  v += __shfl_xor(v, 4); v += __shfl_xor(v, 8);
  return v;
}

DEV unsigned int pk_bf16(float lo, float hi) {
  unsigned int r;
  asm("v_cvt_pk_bf16_f32 %0, %1, %2" : "=v"(r) : "v"(lo), "v"(hi));
  return r;
}

DEV float fast_exp2(float x) {
#if __has_builtin(__builtin_amdgcn_exp2f)
  return __builtin_amdgcn_exp2f(x);
#else
  return __expf(x * 0.6931471805599453f);
#endif
}

DEV void cmulc(float ar, float ai, float br, float bi, float& cr, float& ci) {
  cr = ar * br - ai * bi; ci = ar * bi + ai * br;
}
DEV void mat2mul(const float* A, const float* B, float* C) { // 2x2 complex, C=A*B
  for (int i = 0; i < 2; ++i)
    for (int j = 0; j < 2; ++j) {
      float sr = 0.f, si = 0.f;
      for (int kk = 0; kk < 2; ++kk) {
        float pr, pi;
        cmulc(A[(i * 2 + kk) * 2], A[(i * 2 + kk) * 2 + 1],
              B[(kk * 2 + j) * 2], B[(kk * 2 + j) * 2 + 1], pr, pi);
        sr += pr; si += pi;
      }
      C[(i * 2 + j) * 2] = sr; C[(i * 2 + j) * 2 + 1] = si;
    }
}

// === fused prep: blocks 0-287 weight transposes; blocks 288-299 gate+unitary ===
__global__ __launch_bounds__(256) void prep_all_kernel(
    const float* __restrict__ conv_w, const float* __restrict__ wq,
    const float* __restrict__ wk, const float* __restrict__ wv,
    const float* __restrict__ wo, const float* __restrict__ w1,
    const float* __restrict__ w2,
    const float* __restrict__ enc_w, const float* __restrict__ q_w,
    const float* __restrict__ k_w, const float* __restrict__ v_w,
    const float* __restrict__ mq, const float* __restrict__ mk,
    const float* __restrict__ mv, float* __restrict__ ws) {
  __shared__ float Ulds[288];
  int bx = blockIdx.x;
  int tid = threadIdx.x;
  if (bx < 288) {
    int g = bx * 256 + tid;
    if (g < 24576) {
      int kk = g / 384, o = g % 384;
      ws[OFF_TR + g] = conv_w[o * 64 + kk];
    } else if (g < 40960) {
      int i = g - 24576;
      int m = i >> 12;
      int r = i & 4095;
      int d = r >> 6, o = r & 63;
      const float* src = m == 0 ? wq : m == 1 ? wk : m == 2 ? wv : wo;
      ws[OFF_WQT + i] = src[o * 64 + d];
    } else if (g < 57344) {
      int i = g - 40960;            // w2p[u4][o][j] = w2[o][u4*4+j]
      int u4 = i >> 8, r = i & 255, o = r >> 2, j = r & 3;
      ws[OFF_W2P + i] = w2[o * 256 + u4 * 4 + j];
    } else if (g < 73728) {
      int i = g - 57344;            // w1p[d4][u][j] = w1[u][d4*4+j]
      int d4 = i >> 10, r = i & 1023, u = r >> 2, j = r & 3;
      ws[OFF_W1P + i] = w1[u * 64 + d4 * 4 + j];
    }
    return;
  }
  // ---- ubuild blocks ----
  int ub = bx - 288;                // 0..11
  int branch = ub >> 2, quad = ub & 3;
  const float* bw = branch == 0 ? q_w : branch == 1 ? k_w : v_w;
  const float* mw = branch == 0 ? mq : branch == 1 ? mk : mv;
  if (tid < 36) {
    int blk = tid / 6, wire = tid % 6;
    auto W = [&](int l, int t) -> float {
      if (l <= 1) return enc_w[(l * 6 + wire) * 3 + t];
      if (l <= 3) return bw[((l - 2) * 6 + wire) * 3 + t];
      return mw[wire * 3 + t];
    };
    auto mk_rx = [](float th, float* M) {
      float c = cosf(0.5f * th), s = sinf(0.5f * th);
      M[0] = c; M[1] = 0; M[2] = 0; M[3] = -s; M[4] = 0; M[5] = -s; M[6] = c; M[7] = 0;
    };
    auto mk_ry = [](float th, float* M) {
      float c = cosf(0.5f * th), s = sinf(0.5f * th);
      M[0] = c; M[1] = 0; M[2] = -s; M[3] = 0; M[4] = s; M[5] = 0; M[6] = c; M[7] = 0;
    };
    float R[8];
    if (blk == 0) {           // RY1(W0)*RX(W0)
      float Am[8], Bx[8];
      mk_ry(W(0, 1), Am); mk_rx(W(0, 0), Bx);
      mat2mul(Am, Bx, R);
    } else if (blk <= 4) {    // RY1(Wb)*RX(Wb)*RY2(W{b-1})
      float Am[8], Bx[8], C[8], T[8];
      mk_ry(W(blk, 1), Am); mk_rx(W(blk, 0), Bx); mk_ry(W(blk - 1, 2), C);
      mat2mul(Bx, C, T); mat2mul(Am, T, R);
    } else {                  // RY2(W4)
      mk_ry(W(4, 2), R);
    }
#pragma unroll
    for (int t = 0; t < 8; ++t) Ulds[(blk * 6 + wire) * 8 + t] = R[t];
  }
  __syncthreads();
  if (tid >= 64) return;
  int s = tid & 3;
  int lane = tid;
  int c = quad * 16 + (tid >> 2);
  bool bit1 = (s & 2) != 0;
  bool bit0 = (s & 1) != 0;
  float re[16], im[16];
#pragma unroll
  for (int i = 0; i < 16; ++i) { re[i] = (s * 16 + i == c) ? 1.f : 0.f; im[i] = 0.f; }
#pragma unroll 1
  for (int blk = 0; blk < 6; ++blk) {
    const float* Uw = Ulds + blk * 48;
    {
      const float* M = Uw;
      float cAr = bit1 ? M[6] : M[0], cAi = bit1 ? M[7] : M[1];
      float cBr = bit1 ? M[4] : M[2], cBi = bit1 ? M[5] : M[3];
#pragma unroll
      for (int i = 0; i < 16; ++i) {
        float pr = __shfl_xor(re[i], 2);
        float pi = __shfl_xor(im[i], 2);
        float nr = cAr * re[i] - cAi * im[i] + cBr * pr - cBi * pi;
        float ni = cAr * im[i] + cAi * re[i] + cBr * pi + cBi * pr;
        re[i] = nr; im[i] = ni;
      }
    }
    {
      const float* M = Uw + 8;
      float cAr = bit0 ? M[6] : M[0], cAi = bit0 ? M[7] : M[1];
      float cBr = bit0 ? M[4] : M[2], cBi = bit0 ? M[5] : M[3];
#pragma unroll
      for (int i = 0; i < 16; ++i) {
        float pr = __shfl_xor(re[i], 1);
        float pi = __shfl_xor(im[i], 1);
        float nr = cAr * re[i] - cAi * im[i] + cBr * pr - cBi * pi;
        float ni = cAr * im[i] + cAi * re[i] + cBr * pi + cBi * pr;
        re[i] = nr; im[i] = ni;
      }
    }
#pragma unroll
    for (int w = 2; w < 6; ++w) {
      const float* M = Uw + w * 8;
      const float m0 = M[0], m1 = M[1], m2 = M[2], m3 = M[3];
      const float m4 = M[4], m5 = M[5], m6 = M[6], m7 = M[7];
      const int mm = 8 >> (w - 2);
#pragma unroll
      for (int i = 0; i < 16; ++i) {
        if (i & mm) continue;
        int i1 = i | mm;
        float ar = re[i], ai = im[i], br = re[i1], bi = im[i1];
        re[i]  = m0 * ar - m1 * ai + m2 * br - m3 * bi;
        im[i]  = m0 * ai + m1 * ar + m2 * bi + m3 * br;
        re[i1] = m4 * ar - m5 * ai + m6 * br - m7 * bi;
        im[i1] = m4 * ai + m5 * ar + m6 * bi + m7 * br;
      }
    }
    if (blk < 5) {
      int sl = (lane & ~3) | (bit1 ? (s ^ 1) : s);
      float tr[16], ti[16];
#pragma unroll
      for (int i = 0; i < 16; ++i) {
        tr[i] = __shfl(re[i], sl);
        ti[i] = __shfl(im[i], sl);
      }
#pragma unroll
      for (int i = 0; i < 16; ++i) {
        int j = i;
        if (j & 2) j ^= 1;
        if (j & 4) j ^= 2;
        if (j & 8) j ^= 4;
        re[i] = bit0 ? tr[j ^ 8] : tr[j];
        im[i] = bit0 ? ti[j ^ 8] : ti[j];
      }
    }
  }
  float* dre = ws + OFF_UT + (size_t)branch * 8192 + c * 64 + s * 16;
  float* dim = dre + 4096;
#pragma unroll
  for (int i = 0; i < 16; i += 4) {
    f4 r4 = {re[i], re[i + 1], re[i + 2], re[i + 3]};
    f4 i4 = {im[i], im[i + 1], im[i + 2], im[i + 3]};
    *(f4*)(dre + i) = r4;
    *(f4*)(dim + i) = i4;
  }
}

// == fused patch embed + LN1/QKV: 512 blocks (256 token-tiles x 2 halves) ==
// half 0: t384 cols 0-191, t64 store, Q; half 1: t384 cols 192-383, K and V.
// hinS padded to [16][68]: wave's 4 tt-groups hit 4 distinct banks (was 4-way).
__global__ __launch_bounds__(256) void patchqkv_kernel(const float* __restrict__ x,
    const float* __restrict__ cwT, const float* __restrict__ conv_b,
    const float* __restrict__ wqT, const float* __restrict__ wkT,
    const float* __restrict__ wvT,
    const float* __restrict__ g1, const float* __restrict__ b1,
    float* __restrict__ out, float* __restrict__ t64,
    float* __restrict__ qo, float* __restrict__ ko, float* __restrict__ vo) {
  __shared__ float A[64][73];    // [k][tok]
  __shared__ float scl[64];
  __shared__ float hinS[16][68]; // 68-pad: conflict-free tt-group reads
  __shared__ float wS[8192];     // half0: wqT | half1: wkT,wvT
  int tid = threadIdx.x;
  int tb = blockIdx.x >> 1;
  int half = blockIdx.x & 1;
  int b = tb >> 4;
  int l0 = (tb & 15) << 6;
  if (half == 0) {
#pragma unroll
    for (int p = 0; p < 16; ++p) wS[p * 256 + tid] = wqT[p * 256 + tid];
  } else {
#pragma unroll
    for (int p = 0; p < 16; ++p) {
      wS[p * 256 + tid] = wkT[p * 256 + tid];
      wS[4096 + p * 256 + tid] = wvT[p * 256 + tid];
    }
  }
  int seg = tid & 15;
  int c = seg >> 2, ph = seg & 3;
#pragma unroll
  for (int r = 0; r < 4; ++r) {
    int tok = (tid >> 4) + (r << 4);
    int l = l0 + tok, hp = l >> 5, wp = l & 31;
    f4 v4 = *(const f4*)(x + (size_t)((b * 4 + c) * 128 + hp * 4 + ph) * 128 + wp * 4);
    A[seg * 4 + 0][tok] = v4.x;
    A[seg * 4 + 1][tok] = v4.y;
    A[seg * 4 + 2][tok] = v4.z;
    A[seg * 4 + 3][tok] = v4.w;
  }
  __syncthreads();
  if (tid < 64) {
    float ss = 0.f;
#pragma unroll
    for (int kk = 0; kk < 64; ++kk) { float vv = A[kk][tid]; ss += vv * vv; }
    scl[tid] = 1.0f / (sqrtf(ss) + EPSn);
  }
  __syncthreads();
  int t0 = tb << 6;
  if (half == 0) {
#pragma unroll
    for (int i = 0; i < 16; ++i) {
      int idx = tid + (i << 8);
      int tok = idx >> 6, kk = idx & 63;
      t64[(size_t)(t0 + tok) * 64 + kk] = A[kk][tok] * scl[tok];
    }
  }
  // ---- t384 GEMM 64x64 @ 64x192 (this half's cols), cwT staged-transpose ----
  {
    int tg = tid >> 4;            // 16 token-groups of 4
    int on = (tid & 15) + half * 16;  // out cols on*12..+12
    float acc[4][12];
#pragma unroll
    for (int i = 0; i < 4; ++i)
#pragma unroll
      for (int jj = 0; jj < 12; ++jj) acc[i][jj] = 0.f;
    for (int kk = 0; kk < 64; ++kk) {
      float a[4];
#pragma unroll
      for (int i = 0; i < 4; ++i) a[i] = A[kk][tg * 4 + i];
      f4 w0 = *(const f4*)(cwT + kk * 384 + on * 12);
      f4 w1 = *(const f4*)(cwT + kk * 384 + on * 12 + 4);
      f4 w2 = *(const f4*)(cwT + kk * 384 + on * 12 + 8);
      float wv_[12] = {w0.x, w0.y, w0.z, w0.w, w1.x, w1.y, w1.z, w1.w,
                       w2.x, w2.y, w2.z, w2.w};
#pragma unroll
      for (int i = 0; i < 4; ++i)
#pragma unroll
        for (int jj = 0; jj < 12; ++jj) acc[i][jj] += a[i] * wv_[jj];
    }
#pragma unroll
    for (int i = 0; i < 4; ++i) {
      int tok = tg * 4 + i;
      size_t basep = (size_t)(t0 + tok) * 448 + on * 12;
#pragma unroll
      for (int jj = 0; jj < 12; ++jj)
        out[basep + jj] = acc[i][jj] + conv_b[on * 12 + jj];
    }
  }
  // ---- LN1 + QKV: 4 passes of 16 tokens; arithmetic identical to qkv_kernel ----
  int tt = tid >> 4, part = tid & 15;
#pragma unroll 1
  for (int pass = 0; pass < 4; ++pass) {
    int tokL = pass * 16 + tt;
    int t = t0 + tokL;
    float sclv = scl[tokL];
    float e0 = A[part * 4 + 0][tokL] * sclv;
    float e1 = A[part * 4 + 1][tokL] * sclv;
    float e2 = A[part * 4 + 2][tokL] * sclv;
    float e3 = A[part * 4 + 3][tokL] * sclv;
    float mean = red16(e0 + e1 + e2 + e3) * 0.015625f;
    float d0 = e0 - mean, d1 = e1 - mean, d2 = e2 - mean, d3 = e3 - mean;
    float var = red16(d0 * d0 + d1 * d1 + d2 * d2 + d3 * d3) * 0.015625f;
    float rs = rsqrtf(var + 1e-5f);
    f4 g4 = *(const f4*)(g1 + part * 4);
    f4 b4 = *(const f4*)(b1 + part * 4);
    f4 hh;
    hh.x = d0 * rs * g4.x + b4.x; hh.y = d1 * rs * g4.y + b4.y;
    hh.z = d2 * rs * g4.z + b4.z; hh.w = d3 * rs * g4.w + b4.w;
    *(f4*)&hinS[tt][part * 4] = hh;
    __syncthreads();
    if (half == 0) {
      float qa0 = 0, qa1 = 0, qa2 = 0, qa3 = 0;
      for (int d = 0; d < 64; ++d) {
        float hd = hinS[tt][d];
        f4 w4 = *(const f4*)&wS[d * 64 + part * 4];
        qa0 += hd * w4.x; qa1 += hd * w4.y; qa2 += hd * w4.z; qa3 += hd * w4.w;
      }
      f4 qr = {qa0, qa1, qa2, qa3};
      *(f4*)(qo + (size_t)t * 64 + part * 4) = qr;
    } else {
      float ka0 = 0, ka1 = 0, ka2 = 0, ka3 = 0;
      float va0 = 0, va1 = 0, va2 = 0, va3 = 0;
      for (int d = 0; d < 64; ++d) {
        float hd = hinS[tt][d];
        f4 wk4 = *(const f4*)&wS[d * 64 + part * 4];
        f4 wv4 = *(const f4*)&wS[4096 + d * 64 + part * 4];
        ka0 += hd * wk4.x; ka1 += hd * wk4.y; ka2 += hd * wk4.z; ka3 += hd * wk4.w;
        va0 += hd * wv4.x; va1 += hd * wv4.y; va2 += hd * wv4.z; va3 += hd * wv4.w;
      }
      f4 kr = {ka0, ka1, ka2, ka3}, vr = {va0, va1, va2, va3};
      *(f4*)(ko + (size_t)t * 64 + part * 4) = kr;
      *(f4*)(vo + (size_t)t * 64 + part * 4) = vr;
    }
    __syncthreads();
  }
}

// ===== classic MHSA: bf16 MFMA flash attention (b128-V, exp2, permlane swap) =====
__global__ __launch_bounds__(256) void attn_kernel(const float* __restrict__ qg,
    const float* __restrict__ kg, const float* __restrict__ vg, float* __restrict__ ao) {
  __shared__ __align__(16) unsigned short Klds[Ln][8];    // 16 KB bf16 (pre-scaled)
  __shared__ __align__(16) unsigned short Vt[10][1032];   // 20.2 KB bf16, d-major (+pad)
  __shared__ __align__(16) unsigned short Qlds[128][8];   // 2 KB bf16
  int bh = blockIdx.x;
  int b = bh >> 3, hh = bh & 7;
  int tid = threadIdx.x;
  int qbase = (blockIdx.y << 7);    // 128 queries per block
  const float* kb = kg + (size_t)(b * Ln) * 64 + hh * 8;
  const float* vb = vg + (size_t)(b * Ln) * 64 + hh * 8;
  const float* qb = qg + (size_t)(b * Ln + qbase) * 64 + hh * 8;
  const float SC = 0.51006944f;     // (1/sqrt(8)) * log2(e), folded into K
#pragma unroll
  for (int p = 0; p < 8; ++p) {
    int e4 = p * 256 + tid;         // 0..2047
    int j = e4 >> 1, part = e4 & 1;
    f4 kv = *(const f4*)(kb + (size_t)j * 64 + part * 4);
    *(uint2*)&Klds[j][part * 4] =
        make_uint2(pk_bf16(kv.x * SC, kv.y * SC), pk_bf16(kv.z * SC, kv.w * SC));
    f4 vv = *(const f4*)(vb + (size_t)j * 64 + part * 4);
    unsigned int u01 = pk_bf16(vv.x, vv.y), u23 = pk_bf16(vv.z, vv.w);
    int d0 = part * 4;
    Vt[d0 + 0][j] = (unsigned short)u01;
    Vt[d0 + 1][j] = (unsigned short)(u01 >> 16);
    Vt[d0 + 2][j] = (unsigned short)u23;
    Vt[d0 + 3][j] = (unsigned short)(u23 >> 16);
  }
#pragma unroll
  for (int p = 0; p < 4; ++p) {
    int j = p * 256 + tid;
    Vt[8][j] = 0x3F80;              // ones row (denominator)
    Vt[9][j] = 0;                   // zero row (clamp target)
  }
  {
    int j = tid >> 1, part = tid & 1;
    f4 qv = *(const f4*)(qb + (size_t)j * 64 + part * 4);
    *(uint2*)&Qlds[j][part * 4] = make_uint2(pk_bf16(qv.x, qv.y), pk_bf16(qv.z, qv.w));
  }
  __syncthreads();

  int l = tid & 63, w = tid >> 6;
  int lq = l & 31;
  bool lo = l < 32;
  const short8 zero8 = {0, 0, 0, 0, 0, 0, 0, 0};
  short8 qf = *(const short8*)&Qlds[w * 32 + lq][0];
  qf = lo ? qf : zero8;
  int d = lq;
  int dc = d > 9 ? 9 : d;
  int vrow0 = (l >> 5) * 8;
  f32x16 acc = {};
  const f32x16 fz = {};
  for (int t = 0; t < 32; ++t) {
    short8 kf = *(const short8*)&Klds[t * 32 + lq][0];
    kf = lo ? kf : zero8;
    f32x16 s = __builtin_amdgcn_mfma_f32_32x32x16_bf16(kf, qf, fz, 0, 0, 0);
    float p[16];
#pragma unroll
    for (int r = 0; r < 16; ++r) p[r] = fast_exp2(s[r]);   // K pre-scaled: p = 2^s
    unsigned int c0 = pk_bf16(p[0], p[1]),  c1 = pk_bf16(p[2], p[3]);
    unsigned int c2 = pk_bf16(p[4], p[5]),  c3 = pk_bf16(p[6], p[7]);
    unsigned int c4 = pk_bf16(p[8], p[9]),  c5 = pk_bf16(p[10], p[11]);
    unsigned int c6 = pk_bf16(p[12], p[13]), c7 = pk_bf16(p[14], p[15]);
    // cross-half exchange via permlane32_swap: X=[a.lo|b.lo], Y=[a.hi|b.hi]
    unsigned int x0 = c0, y0 = c2;
    asm("v_permlane32_swap_b32 %0, %1" : "+v"(x0), "+v"(y0));
    unsigned int x1 = c1, y1 = c3;
    asm("v_permlane32_swap_b32 %0, %1" : "+v"(x1), "+v"(y1));
    unsigned int x4 = c4, y4 = c6;
    asm("v_permlane32_swap_b32 %0, %1" : "+v"(x4), "+v"(y4));
    unsigned int x5 = c5, y5 = c7;
    asm("v_permlane32_swap_b32 %0, %1" : "+v"(x5), "+v"(y5));
    union { u32x4 u; short8 s8; } B0, B1;
    B0.u = (u32x4){x0, x1, y0, y1};   // lo:{c0,c1,pc0,pc1} hi:{pc2,pc3,c2,c3}
    B1.u = (u32x4){x4, x5, y4, y5};   // lo:{c4,c5,pc4,pc5} hi:{pc6,pc7,c6,c7}
    int jb = t * 32 + vrow0;
    short8 av0 = *(const short8*)&Vt[dc][jb];        // ds_read_b128 (aligned)
    short8 av1 = *(const short8*)&Vt[dc][jb + 16];   // ds_read_b128
    acc = __builtin_amdgcn_mfma_f32_32x32x16_bf16(av0, B0.s8, acc, 0, 0, 0);
    acc = __builtin_amdgcn_mfma_f32_32x32x16_bf16(av1, B1.s8, acc, 0, 0, 0);
  }
  float ssum = __shfl(acc[4], lq);
  float inv = 1.0f / ssum;
  f4 o = {acc[0] * inv, acc[1] * inv, acc[2] * inv, acc[3] * inv};
  float* dst = ao + (size_t)(b * Ln + qbase + w * 32 + lq) * 64 + hh * 8 + (lo ? 0 : 4);
  *(f4*)dst = o;
}

// ========= out-proj residual + LN2 + normalize (st); woT staged in LDS =========
__global__ __launch_bounds__(256) void proj_st_kernel(float* __restrict__ t64st,
    const float* __restrict__ ao, const float* __restrict__ woT, const float* __restrict__ bo,
    const float* __restrict__ g2, const float* __restrict__ b2, const float* __restrict__ iscale,
    float* __restrict__ hB) {
  __shared__ float woS[4096];   // 16 KB
  __shared__ float aos[16][68]; // 68-pad: conflict-free tt-group reads
  int tid = threadIdx.x;
#pragma unroll
  for (int p = 0; p < 16; ++p) {
    int idx = p * 256 + tid;
    woS[idx] = woT[idx];
  }
  int t0 = blockIdx.x << 4;
  int tt = tid >> 4, part = tid & 15;
  int t = t0 + tt;
  *(f4*)&aos[tt][part * 4] = *(const f4*)(ao + (size_t)t * 64 + part * 4);
  __syncthreads();
  f4 acc;
  acc.x = bo[part * 4 + 0]; acc.y = bo[part * 4 + 1];
  acc.z = bo[part * 4 + 2]; acc.w = bo[part * 4 + 3];
  for (int d = 0; d < 64; ++d) {
    float ad = aos[tt][d];
    f4 w4 = *(const f4*)&woS[d * 64 + part * 4];
    acc.x += ad * w4.x; acc.y += ad * w4.y; acc.z += ad * w4.z; acc.w += ad * w4.w;
  }
  f4 tv = *(const f4*)(t64st + (size_t)t * 64 + part * 4);
  f4 hv = {tv.x + acc.x, tv.y + acc.y, tv.z + acc.z, tv.w + acc.w};
  *(f4*)(hB + (size_t)t * 64 + part * 4) = hv;
  float mean = red16(hv.x + hv.y + hv.z + hv.w) * 0.015625f;
  float d0 = hv.x - mean, d1 = hv.y - mean, d2 = hv.z - mean, d3 = hv.w - mean;
  float var = red16(d0 * d0 + d1 * d1 + d2 * d2 + d3 * d3) * 0.015625f;
  float rs = rsqrtf(var + 1e-5f);
  f4 g4 = *(const f4*)(g2 + part * 4);
  f4 b4 = *(const f4*)(b2 + part * 4);
  f4 is4 = *(const f4*)(iscale + part * 4);
  float x0 = (d0 * rs * g4.x + b4.x) * is4.x;
  float x1 = (d1 * rs * g4.y + b4.y) * is4.y;
  float x2 = (d2 * rs * g4.z + b4.z) * is4.z;
  float x3 = (d3 * rs * g4.w + b4.w) * is4.w;
  float nrm = sqrtf(red16(x0 * x0 + x1 * x1 + x2 * x2 + x3 * x3));
  float rn = 1.0f / (nrm + EPSn);
  f4 stv = {x0 * rn, x1 * rn, x2 * rn, x3 * rn};
  *(f4*)(t64st + (size_t)t * 64 + part * 4) = stv;
}

// ======== quantum: psi_out = st @ U_total^T as fp32 LDS GEMM + epilogue ========
__global__ __launch_bounds__(256) void quantum_kernel(const float* __restrict__ st,
    const float* __restrict__ ut,
    const float* __restrict__ qproj_w, const float* __restrict__ qproj_b,
    const float* __restrict__ kproj_w, const float* __restrict__ kproj_b,
    const float* __restrict__ qkg, const float* __restrict__ qkb,
    float* __restrict__ qvb, float* __restrict__ kvb, float* __restrict__ v64) {
  __shared__ float smem[12288];     // sts[4096] | ure[4096] | uim[4096]; plds aliases front
  int tid = threadIdx.x;
  int branch = blockIdx.y;
  int t0 = blockIdx.x << 6;         // 64 tokens/block
  const float* ub = ut + (size_t)branch * 8192;
#pragma unroll
  for (int p = 0; p < 16; ++p) {
    int idx = p * 256 + tid;        // 0..4095
    smem[idx] = st[(size_t)t0 * 64 + idx];
    smem[4096 + idx] = ub[idx];
    smem[8192 + idx] = ub[4096 + idx];
  }
  __syncthreads();
  int o = tid & 63, tg = tid >> 6;
  float accre[16], accim[16];
#pragma unroll
  for (int i = 0; i < 16; ++i) { accre[i] = 0.f; accim[i] = 0.f; }
  for (int k4 = 0; k4 < 16; ++k4) {
    float ur[4], ui[4];
#pragma unroll
    for (int j = 0; j < 4; ++j) {
      ur[j] = smem[4096 + (k4 * 4 + j) * 64 + o];   // stride-1 lanes: conflict-free
      ui[j] = smem[8192 + (k4 * 4 + j) * 64 + o];
    }
#pragma unroll
    for (int tt = 0; tt < 16; ++tt) {
      f4 a = *(const f4*)&smem[(tg * 16 + tt) * 64 + k4 * 4];  // broadcast
      accre[tt] += a.x * ur[0] + a.y * ur[1] + a.z * ur[2] + a.w * ur[3];
      accim[tt] += a.x * ui[0] + a.y * ui[1] + a.z * ui[2] + a.w * ui[3];
    }
  }
  __syncthreads();                  // everyone done reading sts/U
#pragma unroll
  for (int tt = 0; tt < 16; ++tt) {
    int t = tg * 16 + tt;
    smem[t * 65 + o] = accre[tt] * accre[tt] + accim[tt] * accim[tt];  // plds (65-pad)
  }
  __syncthreads();
  // ---- remap epilogue: thread (token, quarter s) ----
  int s = tid & 3;
  int tokL = tid >> 2;              // 0..63
  int token = t0 + tokL;
  bool bit1 = (s & 2) != 0;
  bool bit0 = (s & 1) != 0;
  float p[16];
#pragma unroll
  for (int i = 0; i < 16; ++i) p[i] = smem[tokL * 65 + s * 16 + i];
  float lsum = 0.f;
#pragma unroll
  for (int i = 0; i < 16; ++i) lsum += p[i];
  if (branch == 2) {
    float tot = lsum;
    tot += __shfl_xor(tot, 1);
    tot += __shfl_xor(tot, 2);
    float rn = 1.0f / (tot + EPSn);
    float* dst = v64 + (size_t)token * 64 + s * 16;
#pragma unroll
    for (int i = 0; i < 16; i += 4) {
      f4 o4 = {p[i] * rn, p[i + 1] * rn, p[i + 2] * rn, p[i + 3] * rn};
      *(f4*)(dst + i) = o4;
    }
  } else {
    float lz[4] = {0.f, 0.f, 0.f, 0.f};
#pragma unroll
    for (int i = 0; i < 16; ++i) {
      lz[0] += (i & 8) ? -p[i] : p[i];
      lz[1] += (i & 4) ? -p[i] : p[i];
      lz[2] += (i & 2) ? -p[i] : p[i];
      lz[3] += (i & 1) ? -p[i] : p[i];
    }
    float z[6];
    float u0 = bit1 ? -lsum : lsum;
    u0 += __shfl_xor(u0, 1); u0 += __shfl_xor(u0, 2); z[0] = u0;
    float u1 = bit0 ? -lsum : lsum;
    u1 += __shfl_xor(u1, 1); u1 += __shfl_xor(u1, 2); z[1] = u1;
#pragma unroll
    for (int q = 0; q < 4; ++q) {
      float v = lz[q];
      v += __shfl_xor(v, 1); v += __shfl_xor(v, 2);
      z[2 + q] = v;
    }
    const float* pw = branch == 0 ? qproj_w : kproj_w;
    const float* pb = branch == 0 ? qproj_b : kproj_b;
    float pr4[4];
#pragma unroll
    for (int jj = 0; jj < 4; ++jj) {
      float a = pb[jj];
#pragma unroll
      for (int qq = 0; qq < 6; ++qq) a += z[qq] * pw[jj * 6 + qq];
      pr4[jj] = a;
    }
    float mean = (pr4[0] + pr4[1] + pr4[2] + pr4[3]) * 0.25f;
    float var = 0.f;
#pragma unroll
    for (int jj = 0; jj < 4; ++jj) { float dd = pr4[jj] - mean; var += dd * dd; }
    var *= 0.25f;
    float rs = rsqrtf(var + 1e-5f);
    if (s == 0) {
      f4 o4;
      o4.x = (pr4[0] - mean) * rs * qkg[0] + qkb[0];
      o4.y = (pr4[1] - mean) * rs * qkg[1] + qkb[1];
      o4.z = (pr4[2] - mean) * rs * qkg[2] + qkb[2];
      o4.w = (pr4[3] - mean) * rs * qkg[3] + qkb[3];
      *(f4*)((branch == 0 ? qvb : kvb) + (size_t)token * 4) = o4;
    }
  }
}

// ==== RBF kernel attention: bf16 MFMA flash (transposed V, exp2-folded) ====
__global__ __launch_bounds__(256) void rbf_kernel(const float* __restrict__ qvb,
    const float* __restrict__ kvb, const float* __restrict__ v64,
    const float* __restrict__ raw_tau, float* __restrict__ pacc, float* __restrict__ pasum) {
  __shared__ __align__(16) unsigned short Vt[64][520];     // 65 KB bf16, d-major (+pad)
  __shared__ __align__(16) unsigned short kvbs[512][8];    // 8 KB bf16 (pre-scaled, 4+4 zero)
  __shared__ float kks[512];                               // (k.k)/tau * log2e
  int tid = threadIdx.x;
  int q0 = blockIdx.x << 7;          // 128 queries/block (global token index)
  int b = q0 >> 10;
  int kc = blockIdx.y;               // key chunk (512 each)
  float tau = log1pf(__expf(raw_tau[0]));
  const float L2E = 1.4426950408889634f;
  float sck = 2.0f * L2E / tau;      // fold into staged k: s' = (q.k)*sck
  int kbase = b * Ln + (kc << 9);
#pragma unroll
  for (int p = 0; p < 2; ++p) {
    int j = p * 256 + tid;
    f4 kv4 = *(const f4*)(kvb + (size_t)(kbase + j) * 4);
    kks[j] = (kv4.x * kv4.x + kv4.y * kv4.y + kv4.z * kv4.z + kv4.w * kv4.w) * (L2E / tau);
    *(uint4*)&kvbs[j][0] =
        make_uint4(pk_bf16(kv4.x * sck, kv4.y * sck), pk_bf16(kv4.z * sck, kv4.w * sck), 0u, 0u);
  }
#pragma unroll
  for (int it = 0; it < 32; ++it) {
    int idx = it * 256 + tid;        // f4 index over 512*16
    int row = idx >> 4, c4 = idx & 15;
    f4 vv = *(const f4*)(v64 + (size_t)(kbase + row) * 64 + c4 * 4);
    unsigned int u01 = pk_bf16(vv.x, vv.y), u23 = pk_bf16(vv.z, vv.w);
    int d0 = c4 * 4;
    Vt[d0 + 0][row] = (unsigned short)u01;
    Vt[d0 + 1][row] = (unsigned short)(u01 >> 16);
    Vt[d0 + 2][row] = (unsigned short)u23;
    Vt[d0 + 3][row] = (unsigned short)(u23 >> 16);
  }
  __syncthreads();

  int l = tid & 63, w = tid >> 6;
  int lq = l & 31;
  bool lo = l < 32;
  bool hi = !lo;
  const short8 zero8 = {0, 0, 0, 0, 0, 0, 0, 0};
  int qtok = q0 + w * 32 + lq;
  f4 qv4 = *(const f4*)(qvb + (size_t)qtok * 4);
  union { u32x4 u; short8 s8; } Qf;
  Qf.u = (u32x4){pk_bf16(qv4.x, qv4.y), pk_bf16(qv4.z, qv4.w), 0u, 0u};
  short8 qf = lo ? Qf.s8 : zero8;
  int vrow0 = (l >> 5) * 8;
  int dbase = hi ? 4 : 0;
  f32x16 acc0 = {}, acc1 = {};
  const f32x16 fz = {};
  float dsum = 0.f;
  for (int t = 0; t < 16; ++t) {     // 16 tiles x 32 keys
    short8 kf = lo ? *(const short8*)&kvbs[t * 32 + lq][0] : zero8;
    f32x16 s = __builtin_amdgcn_mfma_f32_32x32x16_bf16(kf, qf, fz, 0, 0, 0);
    int rowbase = t * 32 + dbase;
    float p[16];
#pragma unroll
    for (int r = 0; r < 16; ++r) {
      float kkv = kks[rowbase + (r & 3) + 8 * (r >> 2)];
      p[r] = fast_exp2(s[r] - kkv);
      dsum += p[r];
    }
    unsigned int c0 = pk_bf16(p[0], p[1]),  c1 = pk_bf16(p[2], p[3]);
    unsigned int c2 = pk_bf16(p[4], p[5]),  c3 = pk_bf16(p[6], p[7]);
    unsigned int c4 = pk_bf16(p[8], p[9]),  c5 = pk_bf16(p[10], p[11]);
    unsigned int c6 = pk_bf16(p[12], p[13]), c7 = pk_bf16(p[14], p[15]);
    unsigned int x0 = c0, y0 = c2;
    asm("v_permlane32_swap_b32 %0, %1" : "+v"(x0), "+v"(y0));
    unsigned int x1 = c1, y1 = c3;
    asm("v_permlane32_swap_b32 %0, %1" : "+v"(x1), "+v"(y1));
    unsigned int x4 = c4, y4 = c6;
    asm("v_permlane32_swap_b32 %0, %1" : "+v"(x4), "+v"(y4));
    unsigned int x5 = c5, y5 = c7;
    asm("v_permlane32_swap_b32 %0, %1" : "+v"(x5), "+v"(y5));
    union { u32x4 u; short8 s8; } B0, B1;
    B0.u = (u32x4){x0, x1, y0, y1};
    B1.u = (u32x4){x4, x5, y4, y5};
    int jb = t * 32 + vrow0;
    short8 a00 = *(const short8*)&Vt[lq][jb];          // ds_read_b128
    short8 a10 = *(const short8*)&Vt[32 + lq][jb];
    short8 a01 = *(const short8*)&Vt[lq][jb + 16];
    short8 a11 = *(const short8*)&Vt[32 + lq][jb + 16];
    acc0 = __builtin_amdgcn_mfma_f32_32x32x16_bf16(a00, B0.s8, acc0, 0, 0, 0);
    acc1 = __builtin_amdgcn_mfma_f32_32x32x16_bf16(a10, B0.s8, acc1, 0, 0, 0);
    acc0 = __builtin_amdgcn_mfma_f32_32x32x16_bf16(a01, B1.s8, acc0, 0, 0, 0);
    acc1 = __builtin_amdgcn_mfma_f32_32x32x16_bf16(a11, B1.s8, acc1, 0, 0, 0);
  }
  float dtot = dsum + __shfl_xor(dsum, 32);
  if (lo) pasum[(kc << 14) + qtok] = dtot;
  float* pa = pacc + (size_t)kc * 1048576 + (size_t)qtok * 64;
#pragma unroll
  for (int r = 0; r < 16; ++r) {
    int dd = (r & 3) + 8 * (r >> 2) + dbase;
    pa[dd] = acc0[r];
    pa[32 + dd] = acc1[r];
  }
}

// == M0+M1+M2 fused: h += rbf; LN3; hid = gelu(.@w1); out = h + hid@w2 + b2 ==
__global__ __launch_bounds__(256) void m0m1m2_kernel(const float* __restrict__ hB,
    const float* __restrict__ pacc, const float* __restrict__ pasum,
    const float* __restrict__ g3, const float* __restrict__ b3,
    const float* __restrict__ w1p, const float* __restrict__ b1v,
    const float* __restrict__ w2p, const float* __restrict__ b2v,
    float* __restrict__ out) {
  __shared__ float hS[16][64];      // 4 KB: updated h (residual source)
  __shared__ float hmS[16][64];     // 4 KB: LN3 output
  __shared__ float hidS[16][256];   // 16 KB: gelu hidden
  int tid = threadIdx.x;
  int t0 = blockIdx.x << 4;
  {
    int tt = tid >> 4, part = tid & 15;
    int t = t0 + tt;
    f4 hv = *(const f4*)(hB + (size_t)t * 64 + part * 4);
    f4 p0 = *(const f4*)(pacc + (size_t)t * 64 + part * 4);
    f4 p1 = *(const f4*)(pacc + 1048576 + (size_t)t * 64 + part * 4);
    float rden = 1.0f / (pasum[t] + pasum[16384 + t] + EPSn);
    hv.x += (p0.x + p1.x) * rden; hv.y += (p0.y + p1.y) * rden;
    hv.z += (p0.z + p1.z) * rden; hv.w += (p0.w + p1.w) * rden;
    *(f4*)&hS[tt][part * 4] = hv;
    float mean = red16(hv.x + hv.y + hv.z + hv.w) * 0.015625f;
    float d0 = hv.x - mean, d1 = hv.y - mean, d2 = hv.z - mean, d3 = hv.w - mean;
    float var = red16(d0 * d0 + d1 * d1 + d2 * d2 + d3 * d3) * 0.015625f;
    float rs = rsqrtf(var + 1e-5f);
    f4 g4 = *(const f4*)(g3 + part * 4);
    f4 b4 = *(const f4*)(b3 + part * 4);
    f4 o4 = {d0 * rs * g4.x + b4.x, d1 * rs * g4.y + b4.y,
             d2 * rs * g4.z + b4.z, d3 * rs * g4.w + b4.w};
    *(f4*)&hmS[tt][part * 4] = o4;
  }
  __syncthreads();
  // ---- M1: u = tid computes hid[tok][u] for all 16 tokens ----
  {
    int u = tid;
    float wrow[64];
#pragma unroll
    for (int d4 = 0; d4 < 16; ++d4) {
      f4 w4 = *(const f4*)(w1p + d4 * 1024 + u * 4);   // coalesced
      wrow[d4 * 4] = w4.x; wrow[d4 * 4 + 1] = w4.y;
      wrow[d4 * 4 + 2] = w4.z; wrow[d4 * 4 + 3] = w4.w;
    }
    float bias = b1v[u];
    for (int tok = 0; tok < 16; ++tok) {
      const float* hr = hmS[tok];
      float a0 = 0.f, a1 = 0.f, a2 = 0.f, a3 = 0.f;
#pragma unroll
      for (int d = 0; d < 64; d += 4) {
        a0 += hr[d] * wrow[d];
        a1 += hr[d + 1] * wrow[d + 1];
        a2 += hr[d + 2] * wrow[d + 2];
        a3 += hr[d + 3] * wrow[d + 3];
      }
      float a = bias + ((a0 + a1) + (a2 + a3));
      float tz = 0.7978845608028654f * (a + 0.044715f * a * a * a);
      float e = __expf(2.0f * tz);
      float th = 1.0f - 2.0f / (e + 1.0f);
      hidS[tok][u] = 0.5f * a * (1.0f + th);
    }
  }
  __syncthreads();
  // ---- M2: lane owns out col o; 4 token-groups of 4 ----
  int o = tid & 63, tg = tid >> 6;
  f4 acc[4];
#pragma unroll
  for (int tt = 0; tt < 4; ++tt) acc[tt] = {0.f, 0.f, 0.f, 0.f};
#pragma unroll 4
  for (int u4 = 0; u4 < 64; ++u4) {
    f4 wv = *(const f4*)(w2p + u4 * 256 + o * 4);   // coalesced 1KB/wave, L2-hot
#pragma unroll
    for (int tt = 0; tt < 4; ++tt) {
      f4 hv = *(const f4*)&hidS[tg * 4 + tt][u4 * 4];   // broadcast (same addr per wave)
      acc[tt].x += hv.x * wv.x; acc[tt].y += hv.y * wv.y;
      acc[tt].z += hv.z * wv.z; acc[tt].w += hv.w * wv.w;
    }
  }
  float bb = b2v[o];
#pragma unroll
  for (int tt = 0; tt < 4; ++tt) {
    int tok = tg * 4 + tt;
    float r = bb + ((acc[tt].x + acc[tt].y) + (acc[tt].z + acc[tt].w));
    out[(size_t)(t0 + tok) * 448 + 384 + o] = hS[tok][o] + r;
  }
}

// ===================== host =====================
extern "C" void kernel_launch(void* const* d_in, const int* in_sizes, int n_in,
                              void* d_out, int out_size, void* d_ws, size_t ws_size,
                              hipStream_t stream) {
  (void)in_sizes; (void)n_in; (void)out_size; (void)ws_size;
  const float* x       = (const float*)d_in[0];
  const float* conv_w  = (const float*)d_in[1];
  const float* conv_b  = (const float*)d_in[2];
  const float* ln1_g   = (const float*)d_in[3];
  const float* ln1_b   = (const float*)d_in[4];
  const float* wq      = (const float*)d_in[5];
  const float* wk      = (const float*)d_in[6];
  const float* wv      = (const float*)d_in[7];
  const float* wo      = (const float*)d_in[8];
  const float* bo      = (const float*)d_in[9];
  const float* ln2_g   = (const float*)d_in[10];
  const float* ln2_b   = (const float*)d_in[11];
  const float* enc_w   = (const float*)d_in[12];
  const float* q_w     = (const float*)d_in[13];
  const float* k_w     = (const float*)d_in[14];
  const float* v_w     = (const float*)d_in[15];
  const float* mq_w    = (const float*)d_in[16];
  const float* mk_w    = (const float*)d_in[17];
  const float* mv_w    = (const float*)d_in[18];
  const float* qproj_w = (const float*)d_in[19];
  const float* qproj_b = (const float*)d_in[20];
  const float* kproj_w = (const float*)d_in[21];
  const float* kproj_b = (const float*)d_in[22];
  const float* qkln_g  = (const float*)d_in[23];
  const float* qkln_b  = (const float*)d_in[24];
  const float* raw_tau = (const float*)d_in[25];
  const float* iscale  = (const float*)d_in[26];
  const float* ln3_g   = (const float*)d_in[27];
  const float* ln3_b   = (const float*)d_in[28];
  const float* mlp_w1  = (const float*)d_in[29];
  const float* mlp_b1  = (const float*)d_in[30];
  const float* mlp_w2  = (const float*)d_in[31];
  const float* mlp_b2  = (const float*)d_in[32];
  float* out = (float*)d_out;
  float* ws  = (float*)d_ws;

  prep_all_kernel<<<300, 256, 0, stream>>>(conv_w, wq, wk, wv, wo, mlp_w1, mlp_w2,
                                           enc_w, q_w, k_w, v_w, mq_w, mk_w, mv_w, ws);
  patchqkv_kernel<<<512, 256, 0, stream>>>(x, ws + OFF_TR, conv_b,
                                           ws + OFF_WQT, ws + OFF_WKT, ws + OFF_WVT,
                                           ln1_g, ln1_b, out, ws + OFF_T64,
                                           ws + OFF_Q, ws + OFF_K, ws + OFF_V);
  attn_kernel<<<dim3(128, 8), 256, 0, stream>>>(ws + OFF_Q, ws + OFF_K, ws + OFF_V, ws + OFF_AO);
  proj_st_kernel<<<1024, 256, 0, stream>>>(ws + OFF_T64, ws + OFF_AO, ws + OFF_WOT, bo,
                                           ln2_g, ln2_b, iscale, ws + OFF_H);
  quantum_kernel<<<dim3(256, 3), 256, 0, stream>>>(ws + OFF_T64, ws + OFF_UT,
                                                   qproj_w, qproj_b, kproj_w, kproj_b,
                                                   qkln_g, qkln_b,
                                                   ws + OFF_K, ws + OFF_K + 65536, ws + OFF_Q);
  rbf_kernel<<<dim3(128, 2), 256, 0, stream>>>(ws + OFF_K, ws + OFF_K + 65536, ws + OFF_Q,
                                               raw_tau, ws + OFF_V, ws + OFF_K + 131072);
  m0m1m2_kernel<<<1024, 256, 0, stream>>>(ws + OFF_H, ws + OFF_V, ws + OFF_K + 131072,
                                          ln3_g, ln3_b, ws + OFF_W1P, mlp_b1,
                                          ws + OFF_W2P, mlp_b2, out);
}

// Round 30
// 157.712 us; speedup vs baseline: 1.1614x; 1.0278x over previous
//
#include <hip/hip_runtime.h>

typedef float4 f4;
#define DEV static __device__ __forceinline__

constexpr int Ln = 1024;
constexpr float EPSn = 1e-9f;

typedef __attribute__((ext_vector_type(8))) short short8;
typedef __attribute__((ext_vector_type(16))) float f32x16;
typedef __attribute__((ext_vector_type(4))) unsigned int u32x4;

// ---------- ws layout (float offsets) ----------
constexpr size_t OFF_T64 = 0;                  // t64 (read-only after patch)
constexpr size_t OFF_H   = 1048576;            // h
constexpr size_t OFF_Q   = 2097152;            // q -> v64
constexpr size_t OFF_K   = 3145728;            // k -> qvb/kvb/pasum
constexpr size_t OFF_V   = 4194304;            // v -> rbf pacc chunk0
constexpr size_t OFF_AO  = 5242880;            // attnout -> rbf pacc chunk1
constexpr size_t OFF_TR  = 6291456;            // cwT (24576)
constexpr size_t OFF_WQT = OFF_TR + 24576;
constexpr size_t OFF_WKT = OFF_WQT + 4096;
constexpr size_t OFF_WVT = OFF_WKT + 4096;
constexpr size_t OFF_WOT = OFF_WVT + 4096;
constexpr size_t OFF_U   = OFF_WOT + 4096;     // (unused)
constexpr size_t OFF_W2P = OFF_U + 1024;       // w2p[u4][o][4]
constexpr size_t OFF_W1P = OFF_W2P + 16384;    // w1p[d4][u][4]
constexpr size_t OFF_UT  = OFF_W1P + 16384;    // UreT/UimT per branch

DEV float red16(float v) {
  v += __shfl_xor(v, 1); v += __shfl_xor(v, 2);
  v += __shfl_xor(v, 4); v += __shfl_xor(v, 8);
  return v;
}

DEV unsigned int pk_bf16(float lo, float hi) {
  unsigned int r;
  asm("v_cvt_pk_bf16_f32 %0, %1, %2" : "=v"(r) : "v"(lo), "v"(hi));
  return r;
}

DEV float fast_exp2(float x) {
#if __has_builtin(__builtin_amdgcn_exp2f)
  return __builtin_amdgcn_exp2f(x);
#else
  return __expf(x * 0.6931471805599453f);
#endif
}

DEV void cmulc(float ar, float ai, float br, float bi, float& cr, float& ci) {
  cr = ar * br - ai * bi; ci = ar * bi + ai * br;
}
DEV void mat2mul(const float* A, const float* B, float* C) { // 2x2 complex, C=A*B
  for (int i = 0; i < 2; ++i)
    for (int j = 0; j < 2; ++j) {
      float sr = 0.f, si = 0.f;
      for (int kk = 0; kk < 2; ++kk) {
        float pr, pi;
        cmulc(A[(i * 2 + kk) * 2], A[(i * 2 + kk) * 2 + 1],
              B[(kk * 2 + j) * 2], B[(kk * 2 + j) * 2 + 1], pr, pi);
        sr += pr; si += pi;
      }
      C[(i * 2 + j) * 2] = sr; C[(i * 2 + j) * 2 + 1] = si;
    }
}

// === fused prep: blocks 0-287 weight transposes; blocks 288-299 gate+unitary ===
__global__ __launch_bounds__(256) void prep_all_kernel(
    const float* __restrict__ conv_w, const float* __restrict__ wq,
    const float* __restrict__ wk, const float* __restrict__ wv,
    const float* __restrict__ wo, const float* __restrict__ w1,
    const float* __restrict__ w2,
    const float* __restrict__ enc_w, const float* __restrict__ q_w,
    const float* __restrict__ k_w, const float* __restrict__ v_w,
    const float* __restrict__ mq, const float* __restrict__ mk,
    const float* __restrict__ mv, float* __restrict__ ws) {
  __shared__ float Ulds[288];
  int bx = blockIdx.x;
  int tid = threadIdx.x;
  if (bx < 288) {
    int g = bx * 256 + tid;
    if (g < 24576) {
      int kk = g / 384, o = g % 384;
      ws[OFF_TR + g] = conv_w[o * 64 + kk];
    } else if (g < 40960) {
      int i = g - 24576;
      int m = i >> 12;
      int r = i & 4095;
      int d = r >> 6, o = r & 63;
      const float* src = m == 0 ? wq : m == 1 ? wk : m == 2 ? wv : wo;
      ws[OFF_WQT + i] = src[o * 64 + d];
    } else if (g < 57344) {
      int i = g - 40960;            // w2p[u4][o][j] = w2[o][u4*4+j]
      int u4 = i >> 8, r = i & 255, o = r >> 2, j = r & 3;
      ws[OFF_W2P + i] = w2[o * 256 + u4 * 4 + j];
    } else if (g < 73728) {
      int i = g - 57344;            // w1p[d4][u][j] = w1[u][d4*4+j]
      int d4 = i >> 10, r = i & 1023, u = r >> 2, j = r & 3;
      ws[OFF_W1P + i] = w1[u * 64 + d4 * 4 + j];
    }
    return;
  }
  // ---- ubuild blocks ----
  int ub = bx - 288;                // 0..11
  int branch = ub >> 2, quad = ub & 3;
  const float* bw = branch == 0 ? q_w : branch == 1 ? k_w : v_w;
  const float* mw = branch == 0 ? mq : branch == 1 ? mk : mv;
  if (tid < 36) {
    int blk = tid / 6, wire = tid % 6;
    auto W = [&](int l, int t) -> float {
      if (l <= 1) return enc_w[(l * 6 + wire) * 3 + t];
      if (l <= 3) return bw[((l - 2) * 6 + wire) * 3 + t];
      return mw[wire * 3 + t];
    };
    auto mk_rx = [](float th, float* M) {
      float c = cosf(0.5f * th), s = sinf(0.5f * th);
      M[0] = c; M[1] = 0; M[2] = 0; M[3] = -s; M[4] = 0; M[5] = -s; M[6] = c; M[7] = 0;
    };
    auto mk_ry = [](float th, float* M) {
      float c = cosf(0.5f * th), s = sinf(0.5f * th);
      M[0] = c; M[1] = 0; M[2] = -s; M[3] = 0; M[4] = s; M[5] = 0; M[6] = c; M[7] = 0;
    };
    float R[8];
    if (blk == 0) {           // RY1(W0)*RX(W0)
      float Am[8], Bx[8];
      mk_ry(W(0, 1), Am); mk_rx(W(0, 0), Bx);
      mat2mul(Am, Bx, R);
    } else if (blk <= 4) {    // RY1(Wb)*RX(Wb)*RY2(W{b-1})
      float Am[8], Bx[8], C[8], T[8];
      mk_ry(W(blk, 1), Am); mk_rx(W(blk, 0), Bx); mk_ry(W(blk - 1, 2), C);
      mat2mul(Bx, C, T); mat2mul(Am, T, R);
    } else {                  // RY2(W4)
      mk_ry(W(4, 2), R);
    }
#pragma unroll
    for (int t = 0; t < 8; ++t) Ulds[(blk * 6 + wire) * 8 + t] = R[t];
  }
  __syncthreads();
  if (tid >= 64) return;
  int s = tid & 3;
  int lane = tid;
  int c = quad * 16 + (tid >> 2);
  bool bit1 = (s & 2) != 0;
  bool bit0 = (s & 1) != 0;
  float re[16], im[16];
#pragma unroll
  for (int i = 0; i < 16; ++i) { re[i] = (s * 16 + i == c) ? 1.f : 0.f; im[i] = 0.f; }
#pragma unroll 1
  for (int blk = 0; blk < 6; ++blk) {
    const float* Uw = Ulds + blk * 48;
    {
      const float* M = Uw;
      float cAr = bit1 ? M[6] : M[0], cAi = bit1 ? M[7] : M[1];
      float cBr = bit1 ? M[4] : M[2], cBi = bit1 ? M[5] : M[3];
#pragma unroll
      for (int i = 0; i < 16; ++i) {
        float pr = __shfl_xor(re[i], 2);
        float pi = __shfl_xor(im[i], 2);
        float nr = cAr * re[i] - cAi * im[i] + cBr * pr - cBi * pi;
        float ni = cAr * im[i] + cAi * re[i] + cBr * pi + cBi * pr;
        re[i] = nr; im[i] = ni;
      }
    }
    {
      const float* M = Uw + 8;
      float cAr = bit0 ? M[6] : M[0], cAi = bit0 ? M[7] : M[1];
      float cBr = bit0 ? M[4] : M[2], cBi = bit0 ? M[5] : M[3];
#pragma unroll
      for (int i = 0; i < 16; ++i) {
        float pr = __shfl_xor(re[i], 1);
        float pi = __shfl_xor(im[i], 1);
        float nr = cAr * re[i] - cAi * im[i] + cBr * pr - cBi * pi;
        float ni = cAr * im[i] + cAi * re[i] + cBr * pi + cBi * pr;
        re[i] = nr; im[i] = ni;
      }
    }
#pragma unroll
    for (int w = 2; w < 6; ++w) {
      const float* M = Uw + w * 8;
      const float m0 = M[0], m1 = M[1], m2 = M[2], m3 = M[3];
      const float m4 = M[4], m5 = M[5], m6 = M[6], m7 = M[7];
      const int mm = 8 >> (w - 2);
#pragma unroll
      for (int i = 0; i < 16; ++i) {
        if (i & mm) continue;
        int i1 = i | mm;
        float ar = re[i], ai = im[i], br = re[i1], bi = im[i1];
        re[i]  = m0 * ar - m1 * ai + m2 * br - m3 * bi;
        im[i]  = m0 * ai + m1 * ar + m2 * bi + m3 * br;
        re[i1] = m4 * ar - m5 * ai + m6 * br - m7 * bi;
        im[i1] = m4 * ai + m5 * ar + m6 * bi + m7 * br;
      }
    }
    if (blk < 5) {
      int sl = (lane & ~3) | (bit1 ? (s ^ 1) : s);
      float tr[16], ti[16];
#pragma unroll
      for (int i = 0; i < 16; ++i) {
        tr[i] = __shfl(re[i], sl);
        ti[i] = __shfl(im[i], sl);
      }
#pragma unroll
      for (int i = 0; i < 16; ++i) {
        int j = i;
        if (j & 2) j ^= 1;
        if (j & 4) j ^= 2;
        if (j & 8) j ^= 4;
        re[i] = bit0 ? tr[j ^ 8] : tr[j];
        im[i] = bit0 ? ti[j ^ 8] : ti[j];
      }
    }
  }
  float* dre = ws + OFF_UT + (size_t)branch * 8192 + c * 64 + s * 16;
  float* dim = dre + 4096;
#pragma unroll
  for (int i = 0; i < 16; i += 4) {
    f4 r4 = {re[i], re[i + 1], re[i + 2], re[i + 3]};
    f4 i4 = {im[i], im[i + 1], im[i + 2], im[i + 3]};
    *(f4*)(dre + i) = r4;
    *(f4*)(dim + i) = i4;
  }
}

// == fused patch embed + LN1/QKV: 768 blocks (256 token-tiles x 3 types) ==
// type 0: t384 cols 0-191 + t64 + Q; type 1: t384 cols 192-383 + K; type 2: V.
// One 16 KB weight per block => 39.3 KB LDS => 3 resident blocks/CU (12 waves).
__global__ __launch_bounds__(256) void patchqkv_kernel(const float* __restrict__ x,
    const float* __restrict__ cwT, const float* __restrict__ conv_b,
    const float* __restrict__ wqT, const float* __restrict__ wkT,
    const float* __restrict__ wvT,
    const float* __restrict__ g1, const float* __restrict__ b1,
    float* __restrict__ out, float* __restrict__ t64,
    float* __restrict__ qo, float* __restrict__ ko, float* __restrict__ vo) {
  __shared__ float A[64][73];    // [k][tok]
  __shared__ float scl[64];
  __shared__ float hinS[16][68]; // 68-pad: conflict-free tt-group reads
  __shared__ float wS[4096];     // one 64x64 weight matrix
  int tid = threadIdx.x;
  int tb = blockIdx.x / 3;       // token tile (adjacent types share the tile: L2-hot x)
  int type = blockIdx.x % 3;
  int b = tb >> 4;
  int l0 = (tb & 15) << 6;
  {
    const float* wsrc = (type == 0) ? wqT : (type == 1) ? wkT : wvT;
#pragma unroll
    for (int p = 0; p < 16; ++p) wS[p * 256 + tid] = wsrc[p * 256 + tid];
  }
  int seg = tid & 15;
  int c = seg >> 2, ph = seg & 3;
#pragma unroll
  for (int r = 0; r < 4; ++r) {
    int tok = (tid >> 4) + (r << 4);
    int l = l0 + tok, hp = l >> 5, wp = l & 31;
    f4 v4 = *(const f4*)(x + (size_t)((b * 4 + c) * 128 + hp * 4 + ph) * 128 + wp * 4);
    A[seg * 4 + 0][tok] = v4.x;
    A[seg * 4 + 1][tok] = v4.y;
    A[seg * 4 + 2][tok] = v4.z;
    A[seg * 4 + 3][tok] = v4.w;
  }
  __syncthreads();
  if (tid < 64) {
    float ss = 0.f;
#pragma unroll
    for (int kk = 0; kk < 64; ++kk) { float vv = A[kk][tid]; ss += vv * vv; }
    scl[tid] = 1.0f / (sqrtf(ss) + EPSn);
  }
  __syncthreads();
  int t0 = tb << 6;
  if (type == 0) {
#pragma unroll
    for (int i = 0; i < 16; ++i) {
      int idx = tid + (i << 8);
      int tok = idx >> 6, kk = idx & 63;
      t64[(size_t)(t0 + tok) * 64 + kk] = A[kk][tok] * scl[tok];
    }
  }
  // ---- t384 GEMM 64x64 @ 64x192 (types 0,1 only), cwT staged-transpose ----
  if (type < 2) {
    int tg = tid >> 4;            // 16 token-groups of 4
    int on = (tid & 15) + type * 16;  // out cols on*12..+12
    float acc[4][12];
#pragma unroll
    for (int i = 0; i < 4; ++i)
#pragma unroll
      for (int jj = 0; jj < 12; ++jj) acc[i][jj] = 0.f;
    for (int kk = 0; kk < 64; ++kk) {
      float a[4];
#pragma unroll
      for (int i = 0; i < 4; ++i) a[i] = A[kk][tg * 4 + i];
      f4 w0 = *(const f4*)(cwT + kk * 384 + on * 12);
      f4 w1 = *(const f4*)(cwT + kk * 384 + on * 12 + 4);
      f4 w2 = *(const f4*)(cwT + kk * 384 + on * 12 + 8);
      float wv_[12] = {w0.x, w0.y, w0.z, w0.w, w1.x, w1.y, w1.z, w1.w,
                       w2.x, w2.y, w2.z, w2.w};
#pragma unroll
      for (int i = 0; i < 4; ++i)
#pragma unroll
        for (int jj = 0; jj < 12; ++jj) acc[i][jj] += a[i] * wv_[jj];
    }
#pragma unroll
    for (int i = 0; i < 4; ++i) {
      int tok = tg * 4 + i;
      size_t basep = (size_t)(t0 + tok) * 448 + on * 12;
#pragma unroll
      for (int jj = 0; jj < 12; ++jj)
        out[basep + jj] = acc[i][jj] + conv_b[on * 12 + jj];
    }
  }
  // ---- LN1 + one GEMM: 4 passes of 16 tokens; arithmetic identical ----
  int tt = tid >> 4, part = tid & 15;
  float* dst = (type == 0) ? qo : (type == 1) ? ko : vo;
#pragma unroll 1
  for (int pass = 0; pass < 4; ++pass) {
    int tokL = pass * 16 + tt;
    int t = t0 + tokL;
    float sclv = scl[tokL];
    float e0 = A[part * 4 + 0][tokL] * sclv;
    float e1 = A[part * 4 + 1][tokL] * sclv;
    float e2 = A[part * 4 + 2][tokL] * sclv;
    float e3 = A[part * 4 + 3][tokL] * sclv;
    float mean = red16(e0 + e1 + e2 + e3) * 0.015625f;
    float d0 = e0 - mean, d1 = e1 - mean, d2 = e2 - mean, d3 = e3 - mean;
    float var = red16(d0 * d0 + d1 * d1 + d2 * d2 + d3 * d3) * 0.015625f;
    float rs = rsqrtf(var + 1e-5f);
    f4 g4 = *(const f4*)(g1 + part * 4);
    f4 b4 = *(const f4*)(b1 + part * 4);
    f4 hh;
    hh.x = d0 * rs * g4.x + b4.x; hh.y = d1 * rs * g4.y + b4.y;
    hh.z = d2 * rs * g4.z + b4.z; hh.w = d3 * rs * g4.w + b4.w;
    *(f4*)&hinS[tt][part * 4] = hh;
    __syncthreads();
    float a0 = 0, a1 = 0, a2 = 0, a3 = 0;
    for (int d = 0; d < 64; ++d) {
      float hd = hinS[tt][d];
      f4 w4 = *(const f4*)&wS[d * 64 + part * 4];
      a0 += hd * w4.x; a1 += hd * w4.y; a2 += hd * w4.z; a3 += hd * w4.w;
    }
    f4 r = {a0, a1, a2, a3};
    *(f4*)(dst + (size_t)t * 64 + part * 4) = r;
    __syncthreads();
  }
}

// ===== classic MHSA: bf16 MFMA flash attention (b128-V, exp2, permlane swap) =====
__global__ __launch_bounds__(256) void attn_kernel(const float* __restrict__ qg,
    const float* __restrict__ kg, const float* __restrict__ vg, float* __restrict__ ao) {
  __shared__ __align__(16) unsigned short Klds[Ln][8];    // 16 KB bf16 (pre-scaled)
  __shared__ __align__(16) unsigned short Vt[10][1032];   // 20.2 KB bf16, d-major (+pad)
  __shared__ __align__(16) unsigned short Qlds[128][8];   // 2 KB bf16
  int bh = blockIdx.x;
  int b = bh >> 3, hh = bh & 7;
  int tid = threadIdx.x;
  int qbase = (blockIdx.y << 7);    // 128 queries per block
  const float* kb = kg + (size_t)(b * Ln) * 64 + hh * 8;
  const float* vb = vg + (size_t)(b * Ln) * 64 + hh * 8;
  const float* qb = qg + (size_t)(b * Ln + qbase) * 64 + hh * 8;
  const float SC = 0.51006944f;     // (1/sqrt(8)) * log2(e), folded into K
#pragma unroll
  for (int p = 0; p < 8; ++p) {
    int e4 = p * 256 + tid;         // 0..2047
    int j = e4 >> 1, part = e4 & 1;
    f4 kv = *(const f4*)(kb + (size_t)j * 64 + part * 4);
    *(uint2*)&Klds[j][part * 4] =
        make_uint2(pk_bf16(kv.x * SC, kv.y * SC), pk_bf16(kv.z * SC, kv.w * SC));
    f4 vv = *(const f4*)(vb + (size_t)j * 64 + part * 4);
    unsigned int u01 = pk_bf16(vv.x, vv.y), u23 = pk_bf16(vv.z, vv.w);
    int d0 = part * 4;
    Vt[d0 + 0][j] = (unsigned short)u01;
    Vt[d0 + 1][j] = (unsigned short)(u01 >> 16);
    Vt[d0 + 2][j] = (unsigned short)u23;
    Vt[d0 + 3][j] = (unsigned short)(u23 >> 16);
  }
#pragma unroll
  for (int p = 0; p < 4; ++p) {
    int j = p * 256 + tid;
    Vt[8][j] = 0x3F80;              // ones row (denominator)
    Vt[9][j] = 0;                   // zero row (clamp target)
  }
  {
    int j = tid >> 1, part = tid & 1;
    f4 qv = *(const f4*)(qb + (size_t)j * 64 + part * 4);
    *(uint2*)&Qlds[j][part * 4] = make_uint2(pk_bf16(qv.x, qv.y), pk_bf16(qv.z, qv.w));
  }
  __syncthreads();

  int l = tid & 63, w = tid >> 6;
  int lq = l & 31;
  bool lo = l < 32;
  const short8 zero8 = {0, 0, 0, 0, 0, 0, 0, 0};
  short8 qf = *(const short8*)&Qlds[w * 32 + lq][0];
  qf = lo ? qf : zero8;
  int d = lq;
  int dc = d > 9 ? 9 : d;
  int vrow0 = (l >> 5) * 8;
  f32x16 acc = {};
  const f32x16 fz = {};
  for (int t = 0; t < 32; ++t) {
    short8 kf = *(const short8*)&Klds[t * 32 + lq][0];
    kf = lo ? kf : zero8;
    f32x16 s = __builtin_amdgcn_mfma_f32_32x32x16_bf16(kf, qf, fz, 0, 0, 0);
    float p[16];
#pragma unroll
    for (int r = 0; r < 16; ++r) p[r] = fast_exp2(s[r]);   // K pre-scaled: p = 2^s
    unsigned int c0 = pk_bf16(p[0], p[1]),  c1 = pk_bf16(p[2], p[3]);
    unsigned int c2 = pk_bf16(p[4], p[5]),  c3 = pk_bf16(p[6], p[7]);
    unsigned int c4 = pk_bf16(p[8], p[9]),  c5 = pk_bf16(p[10], p[11]);
    unsigned int c6 = pk_bf16(p[12], p[13]), c7 = pk_bf16(p[14], p[15]);
    // cross-half exchange via permlane32_swap: X=[a.lo|b.lo], Y=[a.hi|b.hi]
    unsigned int x0 = c0, y0 = c2;
    asm("v_permlane32_swap_b32 %0, %1" : "+v"(x0), "+v"(y0));
    unsigned int x1 = c1, y1 = c3;
    asm("v_permlane32_swap_b32 %0, %1" : "+v"(x1), "+v"(y1));
    unsigned int x4 = c4, y4 = c6;
    asm("v_permlane32_swap_b32 %0, %1" : "+v"(x4), "+v"(y4));
    unsigned int x5 = c5, y5 = c7;
    asm("v_permlane32_swap_b32 %0, %1" : "+v"(x5), "+v"(y5));
    union { u32x4 u; short8 s8; } B0, B1;
    B0.u = (u32x4){x0, x1, y0, y1};   // lo:{c0,c1,pc0,pc1} hi:{pc2,pc3,c2,c3}
    B1.u = (u32x4){x4, x5, y4, y5};   // lo:{c4,c5,pc4,pc5} hi:{pc6,pc7,c6,c7}
    int jb = t * 32 + vrow0;
    short8 av0 = *(const short8*)&Vt[dc][jb];        // ds_read_b128 (aligned)
    short8 av1 = *(const short8*)&Vt[dc][jb + 16];   // ds_read_b128
    acc = __builtin_amdgcn_mfma_f32_32x32x16_bf16(av0, B0.s8, acc, 0, 0, 0);
    acc = __builtin_amdgcn_mfma_f32_32x32x16_bf16(av1, B1.s8, acc, 0, 0, 0);
  }
  float ssum = __shfl(acc[4], lq);
  float inv = 1.0f / ssum;
  f4 o = {acc[0] * inv, acc[1] * inv, acc[2] * inv, acc[3] * inv};
  float* dst = ao + (size_t)(b * Ln + qbase + w * 32 + lq) * 64 + hh * 8 + (lo ? 0 : 4);
  *(f4*)dst = o;
}

// ========= out-proj residual + LN2 + normalize (st); woT staged in LDS =========
__global__ __launch_bounds__(256) void proj_st_kernel(float* __restrict__ t64st,
    const float* __restrict__ ao, const float* __restrict__ woT, const float* __restrict__ bo,
    const float* __restrict__ g2, const float* __restrict__ b2, const float* __restrict__ iscale,
    float* __restrict__ hB) {
  __shared__ float woS[4096];   // 16 KB
  __shared__ float aos[16][68]; // 68-pad: conflict-free tt-group reads
  int tid = threadIdx.x;
#pragma unroll
  for (int p = 0; p < 16; ++p) {
    int idx = p * 256 + tid;
    woS[idx] = woT[idx];
  }
  int t0 = blockIdx.x << 4;
  int tt = tid >> 4, part = tid & 15;
  int t = t0 + tt;
  *(f4*)&aos[tt][part * 4] = *(const f4*)(ao + (size_t)t * 64 + part * 4);
  __syncthreads();
  f4 acc;
  acc.x = bo[part * 4 + 0]; acc.y = bo[part * 4 + 1];
  acc.z = bo[part * 4 + 2]; acc.w = bo[part * 4 + 3];
  for (int d = 0; d < 64; ++d) {
    float ad = aos[tt][d];
    f4 w4 = *(const f4*)&woS[d * 64 + part * 4];
    acc.x += ad * w4.x; acc.y += ad * w4.y; acc.z += ad * w4.z; acc.w += ad * w4.w;
  }
  f4 tv = *(const f4*)(t64st + (size_t)t * 64 + part * 4);
  f4 hv = {tv.x + acc.x, tv.y + acc.y, tv.z + acc.z, tv.w + acc.w};
  *(f4*)(hB + (size_t)t * 64 + part * 4) = hv;
  float mean = red16(hv.x + hv.y + hv.z + hv.w) * 0.015625f;
  float d0 = hv.x - mean, d1 = hv.y - mean, d2 = hv.z - mean, d3 = hv.w - mean;
  float var = red16(d0 * d0 + d1 * d1 + d2 * d2 + d3 * d3) * 0.015625f;
  float rs = rsqrtf(var + 1e-5f);
  f4 g4 = *(const f4*)(g2 + part * 4);
  f4 b4 = *(const f4*)(b2 + part * 4);
  f4 is4 = *(const f4*)(iscale + part * 4);
  float x0 = (d0 * rs * g4.x + b4.x) * is4.x;
  float x1 = (d1 * rs * g4.y + b4.y) * is4.y;
  float x2 = (d2 * rs * g4.z + b4.z) * is4.z;
  float x3 = (d3 * rs * g4.w + b4.w) * is4.w;
  float nrm = sqrtf(red16(x0 * x0 + x1 * x1 + x2 * x2 + x3 * x3));
  float rn = 1.0f / (nrm + EPSn);
  f4 stv = {x0 * rn, x1 * rn, x2 * rn, x3 * rn};
  *(f4*)(t64st + (size_t)t * 64 + part * 4) = stv;
}

// ======== quantum: psi_out = st @ U_total^T as fp32 LDS GEMM + epilogue ========
__global__ __launch_bounds__(256) void quantum_kernel(const float* __restrict__ st,
    const float* __restrict__ ut,
    const float* __restrict__ qproj_w, const float* __restrict__ qproj_b,
    const float* __restrict__ kproj_w, const float* __restrict__ kproj_b,
    const float* __restrict__ qkg, const float* __restrict__ qkb,
    float* __restrict__ qvb, float* __restrict__ kvb, float* __restrict__ v64) {
  __shared__ float smem[12288];     // sts[4096] | ure[4096] | uim[4096]; plds aliases front
  int tid = threadIdx.x;
  int branch = blockIdx.y;
  int t0 = blockIdx.x << 6;         // 64 tokens/block
  const float* ub = ut + (size_t)branch * 8192;
#pragma unroll
  for (int p = 0; p < 16; ++p) {
    int idx = p * 256 + tid;        // 0..4095
    smem[idx] = st[(size_t)t0 * 64 + idx];
    smem[4096 + idx] = ub[idx];
    smem[8192 + idx] = ub[4096 + idx];
  }
  __syncthreads();
  int o = tid & 63, tg = tid >> 6;
  float accre[16], accim[16];
#pragma unroll
  for (int i = 0; i < 16; ++i) { accre[i] = 0.f; accim[i] = 0.f; }
  for (int k4 = 0; k4 < 16; ++k4) {
    float ur[4], ui[4];
#pragma unroll
    for (int j = 0; j < 4; ++j) {
      ur[j] = smem[4096 + (k4 * 4 + j) * 64 + o];   // stride-1 lanes: conflict-free
      ui[j] = smem[8192 + (k4 * 4 + j) * 64 + o];
    }
#pragma unroll
    for (int tt = 0; tt < 16; ++tt) {
      f4 a = *(const f4*)&smem[(tg * 16 + tt) * 64 + k4 * 4];  // broadcast
      accre[tt] += a.x * ur[0] + a.y * ur[1] + a.z * ur[2] + a.w * ur[3];
      accim[tt] += a.x * ui[0] + a.y * ui[1] + a.z * ui[2] + a.w * ui[3];
    }
  }
  __syncthreads();                  // everyone done reading sts/U
#pragma unroll
  for (int tt = 0; tt < 16; ++tt) {
    int t = tg * 16 + tt;
    smem[t * 65 + o] = accre[tt] * accre[tt] + accim[tt] * accim[tt];  // plds (65-pad)
  }
  __syncthreads();
  // ---- remap epilogue: thread (token, quarter s) ----
  int s = tid & 3;
  int tokL = tid >> 2;              // 0..63
  int token = t0 + tokL;
  bool bit1 = (s & 2) != 0;
  bool bit0 = (s & 1) != 0;
  float p[16];
#pragma unroll
  for (int i = 0; i < 16; ++i) p[i] = smem[tokL * 65 + s * 16 + i];
  float lsum = 0.f;
#pragma unroll
  for (int i = 0; i < 16; ++i) lsum += p[i];
  if (branch == 2) {
    float tot = lsum;
    tot += __shfl_xor(tot, 1);
    tot += __shfl_xor(tot, 2);
    float rn = 1.0f / (tot + EPSn);
    float* dst = v64 + (size_t)token * 64 + s * 16;
#pragma unroll
    for (int i = 0; i < 16; i += 4) {
      f4 o4 = {p[i] * rn, p[i + 1] * rn, p[i + 2] * rn, p[i + 3] * rn};
      *(f4*)(dst + i) = o4;
    }
  } else {
    float lz[4] = {0.f, 0.f, 0.f, 0.f};
#pragma unroll
    for (int i = 0; i < 16; ++i) {
      lz[0] += (i & 8) ? -p[i] : p[i];
      lz[1] += (i & 4) ? -p[i] : p[i];
      lz[2] += (i & 2) ? -p[i] : p[i];
      lz[3] += (i & 1) ? -p[i] : p[i];
    }
    float z[6];
    float u0 = bit1 ? -lsum : lsum;
    u0 += __shfl_xor(u0, 1); u0 += __shfl_xor(u0, 2); z[0] = u0;
    float u1 = bit0 ? -lsum : lsum;
    u1 += __shfl_xor(u1, 1); u1 += __shfl_xor(u1, 2); z[1] = u1;
#pragma unroll
    for (int q = 0; q < 4; ++q) {
      float v = lz[q];
      v += __shfl_xor(v, 1); v += __shfl_xor(v, 2);
      z[2 + q] = v;
    }
    const float* pw = branch == 0 ? qproj_w : kproj_w;
    const float* pb = branch == 0 ? qproj_b : kproj_b;
    float pr4[4];
#pragma unroll
    for (int jj = 0; jj < 4; ++jj) {
      float a = pb[jj];
#pragma unroll
      for (int qq = 0; qq < 6; ++qq) a += z[qq] * pw[jj * 6 + qq];
      pr4[jj] = a;
    }
    float mean = (pr4[0] + pr4[1] + pr4[2] + pr4[3]) * 0.25f;
    float var = 0.f;
#pragma unroll
    for (int jj = 0; jj < 4; ++jj) { float dd = pr4[jj] - mean; var += dd * dd; }
    var *= 0.25f;
    float rs = rsqrtf(var + 1e-5f);
    if (s == 0) {
      f4 o4;
      o4.x = (pr4[0] - mean) * rs * qkg[0] + qkb[0];
      o4.y = (pr4[1] - mean) * rs * qkg[1] + qkb[1];
      o4.z = (pr4[2] - mean) * rs * qkg[2] + qkb[2];
      o4.w = (pr4[3] - mean) * rs * qkg[3] + qkb[3];
      *(f4*)((branch == 0 ? qvb : kvb) + (size_t)token * 4) = o4;
    }
  }
}

// ==== RBF kernel attention: bf16 MFMA flash (transposed V, exp2-folded) ====
__global__ __launch_bounds__(256) void rbf_kernel(const float* __restrict__ qvb,
    const float* __restrict__ kvb, const float* __restrict__ v64,
    const float* __restrict__ raw_tau, float* __restrict__ pacc, float* __restrict__ pasum) {
  __shared__ __align__(16) unsigned short Vt[64][520];     // 65 KB bf16, d-major (+pad)
  __shared__ __align__(16) unsigned short kvbs[512][8];    // 8 KB bf16 (pre-scaled, 4+4 zero)
  __shared__ float kks[512];                               // (k.k)/tau * log2e
  int tid = threadIdx.x;
  int q0 = blockIdx.x << 7;          // 128 queries/block (global token index)
  int b = q0 >> 10;
  int kc = blockIdx.y;               // key chunk (512 each)
  float tau = log1pf(__expf(raw_tau[0]));
  const float L2E = 1.4426950408889634f;
  float sck = 2.0f * L2E / tau;      // fold into staged k: s' = (q.k)*sck
  int kbase = b * Ln + (kc << 9);
#pragma unroll
  for (int p = 0; p < 2; ++p) {
    int j = p * 256 + tid;
    f4 kv4 = *(const f4*)(kvb + (size_t)(kbase + j) * 4);
    kks[j] = (kv4.x * kv4.x + kv4.y * kv4.y + kv4.z * kv4.z + kv4.w * kv4.w) * (L2E / tau);
    *(uint4*)&kvbs[j][0] =
        make_uint4(pk_bf16(kv4.x * sck, kv4.y * sck), pk_bf16(kv4.z * sck, kv4.w * sck), 0u, 0u);
  }
#pragma unroll
  for (int it = 0; it < 32; ++it) {
    int idx = it * 256 + tid;        // f4 index over 512*16
    int row = idx >> 4, c4 = idx & 15;
    f4 vv = *(const f4*)(v64 + (size_t)(kbase + row) * 64 + c4 * 4);
    unsigned int u01 = pk_bf16(vv.x, vv.y), u23 = pk_bf16(vv.z, vv.w);
    int d0 = c4 * 4;
    Vt[d0 + 0][row] = (unsigned short)u01;
    Vt[d0 + 1][row] = (unsigned short)(u01 >> 16);
    Vt[d0 + 2][row] = (unsigned short)u23;
    Vt[d0 + 3][row] = (unsigned short)(u23 >> 16);
  }
  __syncthreads();

  int l = tid & 63, w = tid >> 6;
  int lq = l & 31;
  bool lo = l < 32;
  bool hi = !lo;
  const short8 zero8 = {0, 0, 0, 0, 0, 0, 0, 0};
  int qtok = q0 + w * 32 + lq;
  f4 qv4 = *(const f4*)(qvb + (size_t)qtok * 4);
  union { u32x4 u; short8 s8; } Qf;
  Qf.u = (u32x4){pk_bf16(qv4.x, qv4.y), pk_bf16(qv4.z, qv4.w), 0u, 0u};
  short8 qf = lo ? Qf.s8 : zero8;
  int vrow0 = (l >> 5) * 8;
  int dbase = hi ? 4 : 0;
  f32x16 acc0 = {}, acc1 = {};
  const f32x16 fz = {};
  float dsum = 0.f;
  for (int t = 0; t < 16; ++t) {     // 16 tiles x 32 keys
    short8 kf = lo ? *(const short8*)&kvbs[t * 32 + lq][0] : zero8;
    f32x16 s = __builtin_amdgcn_mfma_f32_32x32x16_bf16(kf, qf, fz, 0, 0, 0);
    int rowbase = t * 32 + dbase;
    float p[16];
#pragma unroll
    for (int r = 0; r < 16; ++r) {
      float kkv = kks[rowbase + (r & 3) + 8 * (r >> 2)];
      p[r] = fast_exp2(s[r] - kkv);
      dsum += p[r];
    }
    unsigned int c0 = pk_bf16(p[0], p[1]),  c1 = pk_bf16(p[2], p[3]);
    unsigned int c2 = pk_bf16(p[4], p[5]),  c3 = pk_bf16(p[6], p[7]);
    unsigned int c4 = pk_bf16(p[8], p[9]),  c5 = pk_bf16(p[10], p[11]);
    unsigned int c6 = pk_bf16(p[12], p[13]), c7 = pk_bf16(p[14], p[15]);
    unsigned int x0 = c0, y0 = c2;
    asm("v_permlane32_swap_b32 %0, %1" : "+v"(x0), "+v"(y0));
    unsigned int x1 = c1, y1 = c3;
    asm("v_permlane32_swap_b32 %0, %1" : "+v"(x1), "+v"(y1));
    unsigned int x4 = c4, y4 = c6;
    asm("v_permlane32_swap_b32 %0, %1" : "+v"(x4), "+v"(y4));
    unsigned int x5 = c5, y5 = c7;
    asm("v_permlane32_swap_b32 %0, %1" : "+v"(x5), "+v"(y5));
    union { u32x4 u; short8 s8; } B0, B1;
    B0.u = (u32x4){x0, x1, y0, y1};
    B1.u = (u32x4){x4, x5, y4, y5};
    int jb = t * 32 + vrow0;
    short8 a00 = *(const short8*)&Vt[lq][jb];          // ds_read_b128
    short8 a10 = *(const short8*)&Vt[32 + lq][jb];
    short8 a01 = *(const short8*)&Vt[lq][jb + 16];
    short8 a11 = *(const short8*)&Vt[32 + lq][jb + 16];
    acc0 = __builtin_amdgcn_mfma_f32_32x32x16_bf16(a00, B0.s8, acc0, 0, 0, 0);
    acc1 = __builtin_amdgcn_mfma_f32_32x32x16_bf16(a10, B0.s8, acc1, 0, 0, 0);
    acc0 = __builtin_amdgcn_mfma_f32_32x32x16_bf16(a01, B1.s8, acc0, 0, 0, 0);
    acc1 = __builtin_amdgcn_mfma_f32_32x32x16_bf16(a11, B1.s8, acc1, 0, 0, 0);
  }
  float dtot = dsum + __shfl_xor(dsum, 32);
  if (lo) pasum[(kc << 14) + qtok] = dtot;
  float* pa = pacc + (size_t)kc * 1048576 + (size_t)qtok * 64;
#pragma unroll
  for (int r = 0; r < 16; ++r) {
    int dd = (r & 3) + 8 * (r >> 2) + dbase;
    pa[dd] = acc0[r];
    pa[32 + dd] = acc1[r];
  }
}

// == M0+M1+M2 fused: h += rbf; LN3; hid = gelu(.@w1); out = h + hid@w2 + b2 ==
__global__ __launch_bounds__(256) void m0m1m2_kernel(const float* __restrict__ hB,
    const float* __restrict__ pacc, const float* __restrict__ pasum,
    const float* __restrict__ g3, const float* __restrict__ b3,
    const float* __restrict__ w1p, const float* __restrict__ b1v,
    const float* __restrict__ w2p, const float* __restrict__ b2v,
    float* __restrict__ out) {
  __shared__ float hS[16][64];      // 4 KB: updated h (residual source)
  __shared__ float hmS[16][64];     // 4 KB: LN3 output
  __shared__ float hidS[16][256];   // 16 KB: gelu hidden
  int tid = threadIdx.x;
  int t0 = blockIdx.x << 4;
  {
    int tt = tid >> 4, part = tid & 15;
    int t = t0 + tt;
    f4 hv = *(const f4*)(hB + (size_t)t * 64 + part * 4);
    f4 p0 = *(const f4*)(pacc + (size_t)t * 64 + part * 4);
    f4 p1 = *(const f4*)(pacc + 1048576 + (size_t)t * 64 + part * 4);
    float rden = 1.0f / (pasum[t] + pasum[16384 + t] + EPSn);
    hv.x += (p0.x + p1.x) * rden; hv.y += (p0.y + p1.y) * rden;
    hv.z += (p0.z + p1.z) * rden; hv.w += (p0.w + p1.w) * rden;
    *(f4*)&hS[tt][part * 4] = hv;
    float mean = red16(hv.x + hv.y + hv.z + hv.w) * 0.015625f;
    float d0 = hv.x - mean, d1 = hv.y - mean, d2 = hv.z - mean, d3 = hv.w - mean;
    float var = red16(d0 * d0 + d1 * d1 + d2 * d2 + d3 * d3) * 0.015625f;
    float rs = rsqrtf(var + 1e-5f);
    f4 g4 = *(const f4*)(g3 + part * 4);
    f4 b4 = *(const f4*)(b3 + part * 4);
    f4 o4 = {d0 * rs * g4.x + b4.x, d1 * rs * g4.y + b4.y,
             d2 * rs * g4.z + b4.z, d3 * rs * g4.w + b4.w};
    *(f4*)&hmS[tt][part * 4] = o4;
  }
  __syncthreads();
  // ---- M1: u = tid computes hid[tok][u] for all 16 tokens ----
  {
    int u = tid;
    float wrow[64];
#pragma unroll
    for (int d4 = 0; d4 < 16; ++d4) {
      f4 w4 = *(const f4*)(w1p + d4 * 1024 + u * 4);   // coalesced
      wrow[d4 * 4] = w4.x; wrow[d4 * 4 + 1] = w4.y;
      wrow[d4 * 4 + 2] = w4.z; wrow[d4 * 4 + 3] = w4.w;
    }
    float bias = b1v[u];
    for (int tok = 0; tok < 16; ++tok) {
      const float* hr = hmS[tok];
      float a0 = 0.f, a1 = 0.f, a2 = 0.f, a3 = 0.f;
#pragma unroll
      for (int d = 0; d < 64; d += 4) {
        a0 += hr[d] * wrow[d];
        a1 += hr[d + 1] * wrow[d + 1];
        a2 += hr[d + 2] * wrow[d + 2];
        a3 += hr[d + 3] * wrow[d + 3];
      }
      float a = bias + ((a0 + a1) + (a2 + a3));
      float tz = 0.7978845608028654f * (a + 0.044715f * a * a * a);
      float e = __expf(2.0f * tz);
      float th = 1.0f - 2.0f / (e + 1.0f);
      hidS[tok][u] = 0.5f * a * (1.0f + th);
    }
  }
  __syncthreads();
  // ---- M2: lane owns out col o; 4 token-groups of 4 ----
  int o = tid & 63, tg = tid >> 6;
  f4 acc[4];
#pragma unroll
  for (int tt = 0; tt < 4; ++tt) acc[tt] = {0.f, 0.f, 0.f, 0.f};
#pragma unroll 4
  for (int u4 = 0; u4 < 64; ++u4) {
    f4 wv = *(const f4*)(w2p + u4 * 256 + o * 4);   // coalesced 1KB/wave, L2-hot
#pragma unroll
    for (int tt = 0; tt < 4; ++tt) {
      f4 hv = *(const f4*)&hidS[tg * 4 + tt][u4 * 4];   // broadcast (same addr per wave)
      acc[tt].x += hv.x * wv.x; acc[tt].y += hv.y * wv.y;
      acc[tt].z += hv.z * wv.z; acc[tt].w += hv.w * wv.w;
    }
  }
  float bb = b2v[o];
#pragma unroll
  for (int tt = 0; tt < 4; ++tt) {
    int tok = tg * 4 + tt;
    float r = bb + ((acc[tt].x + acc[tt].y) + (acc[tt].z + acc[tt].w));
    out[(size_t)(t0 + tok) * 448 + 384 + o] = hS[tok][o] + r;
  }
}

// ===================== host =====================
extern "C" void kernel_launch(void* const* d_in, const int* in_sizes, int n_in,
                              void* d_out, int out_size, void* d_ws, size_t ws_size,
                              hipStream_t stream) {
  (void)in_sizes; (void)n_in; (void)out_size; (void)ws_size;
  const float* x       = (const float*)d_in[0];
  const float* conv_w  = (const float*)d_in[1];
  const float* conv_b  = (const float*)d_in[2];
  const float* ln1_g   = (const float*)d_in[3];
  const float* ln1_b   = (const float*)d_in[4];
  const float* wq      = (const float*)d_in[5];
  const float* wk      = (const float*)d_in[6];
  const float* wv      = (const float*)d_in[7];
  const float* wo      = (const float*)d_in[8];
  const float* bo      = (const float*)d_in[9];
  const float* ln2_g   = (const float*)d_in[10];
  const float* ln2_b   = (const float*)d_in[11];
  const float* enc_w   = (const float*)d_in[12];
  const float* q_w     = (const float*)d_in[13];
  const float* k_w     = (const float*)d_in[14];
  const float* v_w     = (const float*)d_in[15];
  const float* mq_w    = (const float*)d_in[16];
  const float* mk_w    = (const float*)d_in[17];
  const float* mv_w    = (const float*)d_in[18];
  const float* qproj_w = (const float*)d_in[19];
  const float* qproj_b = (const float*)d_in[20];
  const float* kproj_w = (const float*)d_in[21];
  const float* kproj_b = (const float*)d_in[22];
  const float* qkln_g  = (const float*)d_in[23];
  const float* qkln_b  = (const float*)d_in[24];
  const float* raw_tau = (const float*)d_in[25];
  const float* iscale  = (const float*)d_in[26];
  const float* ln3_g   = (const float*)d_in[27];
  const float* ln3_b   = (const float*)d_in[28];
  const float* mlp_w1  = (const float*)d_in[29];
  const float* mlp_b1  = (const float*)d_in[30];
  const float* mlp_w2  = (const float*)d_in[31];
  const float* mlp_b2  = (const float*)d_in[32];
  float* out = (float*)d_out;
  float* ws  = (float*)d_ws;

  prep_all_kernel<<<300, 256, 0, stream>>>(conv_w, wq, wk, wv, wo, mlp_w1, mlp_w2,
                                           enc_w, q_w, k_w, v_w, mq_w, mk_w, mv_w, ws);
  patchqkv_kernel<<<768, 256, 0, stream>>>(x, ws + OFF_TR, conv_b,
                                           ws + OFF_WQT, ws + OFF_WKT, ws + OFF_WVT,
                                           ln1_g, ln1_b, out, ws + OFF_T64,
                                           ws + OFF_Q, ws + OFF_K, ws + OFF_V);
  attn_kernel<<<dim3(128, 8), 256, 0, stream>>>(ws + OFF_Q, ws + OFF_K, ws + OFF_V, ws + OFF_AO);
  proj_st_kernel<<<1024, 256, 0, stream>>>(ws + OFF_T64, ws + OFF_AO, ws + OFF_WOT, bo,
                                           ln2_g, ln2_b, iscale, ws + OFF_H);
  quantum_kernel<<<dim3(256, 3), 256, 0, stream>>>(ws + OFF_T64, ws + OFF_UT,
                                                   qproj_w, qproj_b, kproj_w, kproj_b,
                                                   qkln_g, qkln_b,
                                                   ws + OFF_K, ws + OFF_K + 65536, ws + OFF_Q);
  rbf_kernel<<<dim3(128, 2), 256, 0, stream>>>(ws + OFF_K, ws + OFF_K + 65536, ws + OFF_Q,
                                               raw_tau, ws + OFF_V, ws + OFF_K + 131072);
  m0m1m2_kernel<<<1024, 256, 0, stream>>>(ws + OFF_H, ws + OFF_V, ws + OFF_K + 131072,
                                          ln3_g, ln3_b, ws + OFF_W1P, mlp_b1,
                                          ws + OFF_W2P, mlp_b2, out);
}

// Round 31
// 157.591 us; speedup vs baseline: 1.1623x; 1.0008x over previous
//
#include <hip/hip_runtime.h>

typedef float4 f4;
#define DEV static __device__ __forceinline__

constexpr int Ln = 1024;
constexpr float EPSn = 1e-9f;

typedef __attribute__((ext_vector_type(8))) short short8;
typedef __attribute__((ext_vector_type(16))) float f32x16;
typedef __attribute__((ext_vector_type(4))) unsigned int u32x4;

// ---------- ws layout (float offsets) ----------
constexpr size_t OFF_T64 = 0;                  // t64 (read-only after patch)
constexpr size_t OFF_H   = 1048576;            // h
constexpr size_t OFF_Q   = 2097152;            // q -> v64
constexpr size_t OFF_K   = 3145728;            // k -> qvb/kvb/pasum
constexpr size_t OFF_V   = 4194304;            // v -> rbf pacc chunk0
constexpr size_t OFF_AO  = 5242880;            // attnout -> rbf pacc chunk1
constexpr size_t OFF_TR  = 6291456;            // cwT (24576)
constexpr size_t OFF_WQT = OFF_TR + 24576;
constexpr size_t OFF_WKT = OFF_WQT + 4096;
constexpr size_t OFF_WVT = OFF_WKT + 4096;
constexpr size_t OFF_WOT = OFF_WVT + 4096;
constexpr size_t OFF_U   = OFF_WOT + 4096;     // (unused)
constexpr size_t OFF_W2P = OFF_U + 1024;       // w2p[u4][o][4]
constexpr size_t OFF_W1P = OFF_W2P + 16384;    // w1p[d4][u][4]
constexpr size_t OFF_UT  = OFF_W1P + 16384;    // UreT/UimT per branch

DEV float red16(float v) {
  v += __shfl_xor(v, 1); v += __shfl_xor(v, 2);
  v += __shfl_xor(v, 4); v += __shfl_xor(v, 8);
  return v;
}

DEV unsigned int pk_bf16(float lo, float hi) {
  unsigned int r;
  asm("v_cvt_pk_bf16_f32 %0, %1, %2" : "=v"(r) : "v"(lo), "v"(hi));
  return r;
}

DEV float fast_exp2(float x) {
#if __has_builtin(__builtin_amdgcn_exp2f)
  return __builtin_amdgcn_exp2f(x);
#else
  return __expf(x * 0.6931471805599453f);
#endif
}

DEV void cmulc(float ar, float ai, float br, float bi, float& cr, float& ci) {
  cr = ar * br - ai * bi; ci = ar * bi + ai * br;
}
DEV void mat2mul(const float* A, const float* B, float* C) { // 2x2 complex, C=A*B
  for (int i = 0; i < 2; ++i)
    for (int j = 0; j < 2; ++j) {
      float sr = 0.f, si = 0.f;
      for (int kk = 0; kk < 2; ++kk) {
        float pr, pi;
        cmulc(A[(i * 2 + kk) * 2], A[(i * 2 + kk) * 2 + 1],
              B[(kk * 2 + j) * 2], B[(kk * 2 + j) * 2 + 1], pr, pi);
        sr += pr; si += pi;
      }
      C[(i * 2 + j) * 2] = sr; C[(i * 2 + j) * 2 + 1] = si;
    }
}

// === fused prep: blocks 0-287 weight transposes; blocks 288-299 gate+unitary ===
__global__ __launch_bounds__(256) void prep_all_kernel(
    const float* __restrict__ conv_w, const float* __restrict__ wq,
    const float* __restrict__ wk, const float* __restrict__ wv,
    const float* __restrict__ wo, const float* __restrict__ w1,
    const float* __restrict__ w2,
    const float* __restrict__ enc_w, const float* __restrict__ q_w,
    const float* __restrict__ k_w, const float* __restrict__ v_w,
    const float* __restrict__ mq, const float* __restrict__ mk,
    const float* __restrict__ mv, float* __restrict__ ws) {
  __shared__ float Ulds[288];
  int bx = blockIdx.x;
  int tid = threadIdx.x;
  if (bx < 288) {
    int g = bx * 256 + tid;
    if (g < 24576) {
      int kk = g / 384, o = g % 384;
      ws[OFF_TR + g] = conv_w[o * 64 + kk];
    } else if (g < 40960) {
      int i = g - 24576;
      int m = i >> 12;
      int r = i & 4095;
      int d = r >> 6, o = r & 63;
      const float* src = m == 0 ? wq : m == 1 ? wk : m == 2 ? wv : wo;
      ws[OFF_WQT + i] = src[o * 64 + d];
    } else if (g < 57344) {
      int i = g - 40960;            // w2p[u4][o][j] = w2[o][u4*4+j]
      int u4 = i >> 8, r = i & 255, o = r >> 2, j = r & 3;
      ws[OFF_W2P + i] = w2[o * 256 + u4 * 4 + j];
    } else if (g < 73728) {
      int i = g - 57344;            // w1p[d4][u][j] = w1[u][d4*4+j]
      int d4 = i >> 10, r = i & 1023, u = r >> 2, j = r & 3;
      ws[OFF_W1P + i] = w1[u * 64 + d4 * 4 + j];
    }
    return;
  }
  // ---- ubuild blocks ----
  int ub = bx - 288;                // 0..11
  int branch = ub >> 2, quad = ub & 3;
  const float* bw = branch == 0 ? q_w : branch == 1 ? k_w : v_w;
  const float* mw = branch == 0 ? mq : branch == 1 ? mk : mv;
  if (tid < 36) {
    int blk = tid / 6, wire = tid % 6;
    auto W = [&](int l, int t) -> float {
      if (l <= 1) return enc_w[(l * 6 + wire) * 3 + t];
      if (l <= 3) return bw[((l - 2) * 6 + wire) * 3 + t];
      return mw[wire * 3 + t];
    };
    auto mk_rx = [](float th, float* M) {
      float c = cosf(0.5f * th), s = sinf(0.5f * th);
      M[0] = c; M[1] = 0; M[2] = 0; M[3] = -s; M[4] = 0; M[5] = -s; M[6] = c; M[7] = 0;
    };
    auto mk_ry = [](float th, float* M) {
      float c = cosf(0.5f * th), s = sinf(0.5f * th);
      M[0] = c; M[1] = 0; M[2] = -s; M[3] = 0; M[4] = s; M[5] = 0; M[6] = c; M[7] = 0;
    };
    float R[8];
    if (blk == 0) {           // RY1(W0)*RX(W0)
      float Am[8], Bx[8];
      mk_ry(W(0, 1), Am); mk_rx(W(0, 0), Bx);
      mat2mul(Am, Bx, R);
    } else if (blk <= 4) {    // RY1(Wb)*RX(Wb)*RY2(W{b-1})
      float Am[8], Bx[8], C[8], T[8];
      mk_ry(W(blk, 1), Am); mk_rx(W(blk, 0), Bx); mk_ry(W(blk - 1, 2), C);
      mat2mul(Bx, C, T); mat2mul(Am, T, R);
    } else {                  // RY2(W4)
      mk_ry(W(4, 2), R);
    }
#pragma unroll
    for (int t = 0; t < 8; ++t) Ulds[(blk * 6 + wire) * 8 + t] = R[t];
  }
  __syncthreads();
  if (tid >= 64) return;
  int s = tid & 3;
  int lane = tid;
  int c = quad * 16 + (tid >> 2);
  bool bit1 = (s & 2) != 0;
  bool bit0 = (s & 1) != 0;
  float re[16], im[16];
#pragma unroll
  for (int i = 0; i < 16; ++i) { re[i] = (s * 16 + i == c) ? 1.f : 0.f; im[i] = 0.f; }
#pragma unroll 1
  for (int blk = 0; blk < 6; ++blk) {
    const float* Uw = Ulds + blk * 48;
    {
      const float* M = Uw;
      float cAr = bit1 ? M[6] : M[0], cAi = bit1 ? M[7] : M[1];
      float cBr = bit1 ? M[4] : M[2], cBi = bit1 ? M[5] : M[3];
#pragma unroll
      for (int i = 0; i < 16; ++i) {
        float pr = __shfl_xor(re[i], 2);
        float pi = __shfl_xor(im[i], 2);
        float nr = cAr * re[i] - cAi * im[i] + cBr * pr - cBi * pi;
        float ni = cAr * im[i] + cAi * re[i] + cBr * pi + cBi * pr;
        re[i] = nr; im[i] = ni;
      }
    }
    {
      const float* M = Uw + 8;
      float cAr = bit0 ? M[6] : M[0], cAi = bit0 ? M[7] : M[1];
      float cBr = bit0 ? M[4] : M[2], cBi = bit0 ? M[5] : M[3];
#pragma unroll
      for (int i = 0; i < 16; ++i) {
        float pr = __shfl_xor(re[i], 1);
        float pi = __shfl_xor(im[i], 1);
        float nr = cAr * re[i] - cAi * im[i] + cBr * pr - cBi * pi;
        float ni = cAr * im[i] + cAi * re[i] + cBr * pi + cBi * pr;
        re[i] = nr; im[i] = ni;
      }
    }
#pragma unroll
    for (int w = 2; w < 6; ++w) {
      const float* M = Uw + w * 8;
      const float m0 = M[0], m1 = M[1], m2 = M[2], m3 = M[3];
      const float m4 = M[4], m5 = M[5], m6 = M[6], m7 = M[7];
      const int mm = 8 >> (w - 2);
#pragma unroll
      for (int i = 0; i < 16; ++i) {
        if (i & mm) continue;
        int i1 = i | mm;
        float ar = re[i], ai = im[i], br = re[i1], bi = im[i1];
        re[i]  = m0 * ar - m1 * ai + m2 * br - m3 * bi;
        im[i]  = m0 * ai + m1 * ar + m2 * bi + m3 * br;
        re[i1] = m4 * ar - m5 * ai + m6 * br - m7 * bi;
        im[i1] = m4 * ai + m5 * ar + m6 * bi + m7 * br;
      }
    }
    if (blk < 5) {
      int sl = (lane & ~3) | (bit1 ? (s ^ 1) : s);
      float tr[16], ti[16];
#pragma unroll
      for (int i = 0; i < 16; ++i) {
        tr[i] = __shfl(re[i], sl);
        ti[i] = __shfl(im[i], sl);
      }
#pragma unroll
      for (int i = 0; i < 16; ++i) {
        int j = i;
        if (j & 2) j ^= 1;
        if (j & 4) j ^= 2;
        if (j & 8) j ^= 4;
        re[i] = bit0 ? tr[j ^ 8] : tr[j];
        im[i] = bit0 ? ti[j ^ 8] : ti[j];
      }
    }
  }
  float* dre = ws + OFF_UT + (size_t)branch * 8192 + c * 64 + s * 16;
  float* dim = dre + 4096;
#pragma unroll
  for (int i = 0; i < 16; i += 4) {
    f4 r4 = {re[i], re[i + 1], re[i + 2], re[i + 3]};
    f4 i4 = {im[i], im[i + 1], im[i + 2], im[i + 3]};
    *(f4*)(dre + i) = r4;
    *(f4*)(dim + i) = i4;
  }
}

// == fused patch embed + LN1/QKV: 768 blocks, type-major decode ==
// type = i>>8 (0:Q+t384lo+t64, 1:K+t384hi, 2:V); tb = i&255.
// 256==0 mod 8 => all 3 type-copies of a tile land on the same XCD (L2-hot x).
__global__ __launch_bounds__(256) void patchqkv_kernel(const float* __restrict__ x,
    const float* __restrict__ cwT, const float* __restrict__ conv_b,
    const float* __restrict__ wqT, const float* __restrict__ wkT,
    const float* __restrict__ wvT,
    const float* __restrict__ g1, const float* __restrict__ b1,
    float* __restrict__ out, float* __restrict__ t64,
    float* __restrict__ qo, float* __restrict__ ko, float* __restrict__ vo) {
  __shared__ float A[64][73];    // [k][tok]
  __shared__ float scl[64];
  __shared__ float hinS[16][68]; // 68-pad: conflict-free tt-group reads
  __shared__ float wS[4096];     // one 64x64 weight matrix
  int tid = threadIdx.x;
  int type = blockIdx.x >> 8;    // XCD-aligned: tile id in low bits
  int tb = blockIdx.x & 255;
  int b = tb >> 4;
  int l0 = (tb & 15) << 6;
  {
    const float* wsrc = (type == 0) ? wqT : (type == 1) ? wkT : wvT;
#pragma unroll
    for (int p = 0; p < 16; ++p) wS[p * 256 + tid] = wsrc[p * 256 + tid];
  }
  int seg = tid & 15;
  int c = seg >> 2, ph = seg & 3;
#pragma unroll
  for (int r = 0; r < 4; ++r) {
    int tok = (tid >> 4) + (r << 4);
    int l = l0 + tok, hp = l >> 5, wp = l & 31;
    f4 v4 = *(const f4*)(x + (size_t)((b * 4 + c) * 128 + hp * 4 + ph) * 128 + wp * 4);
    A[seg * 4 + 0][tok] = v4.x;
    A[seg * 4 + 1][tok] = v4.y;
    A[seg * 4 + 2][tok] = v4.z;
    A[seg * 4 + 3][tok] = v4.w;
  }
  __syncthreads();
  if (tid < 64) {
    float ss = 0.f;
#pragma unroll
    for (int kk = 0; kk < 64; ++kk) { float vv = A[kk][tid]; ss += vv * vv; }
    scl[tid] = 1.0f / (sqrtf(ss) + EPSn);
  }
  __syncthreads();
  int t0 = tb << 6;
  if (type == 0) {
#pragma unroll
    for (int i = 0; i < 16; ++i) {
      int idx = tid + (i << 8);
      int tok = idx >> 6, kk = idx & 63;
      t64[(size_t)(t0 + tok) * 64 + kk] = A[kk][tok] * scl[tok];
    }
  }
  // ---- t384 GEMM 64x64 @ 64x192 (types 0,1 only), cwT staged-transpose ----
  if (type < 2) {
    int tg = tid >> 4;            // 16 token-groups of 4
    int on = (tid & 15) + type * 16;  // out cols on*12..+12
    float acc[4][12];
#pragma unroll
    for (int i = 0; i < 4; ++i)
#pragma unroll
      for (int jj = 0; jj < 12; ++jj) acc[i][jj] = 0.f;
    for (int kk = 0; kk < 64; ++kk) {
      float a[4];
#pragma unroll
      for (int i = 0; i < 4; ++i) a[i] = A[kk][tg * 4 + i];
      f4 w0 = *(const f4*)(cwT + kk * 384 + on * 12);
      f4 w1 = *(const f4*)(cwT + kk * 384 + on * 12 + 4);
      f4 w2 = *(const f4*)(cwT + kk * 384 + on * 12 + 8);
      float wv_[12] = {w0.x, w0.y, w0.z, w0.w, w1.x, w1.y, w1.z, w1.w,
                       w2.x, w2.y, w2.z, w2.w};
#pragma unroll
      for (int i = 0; i < 4; ++i)
#pragma unroll
        for (int jj = 0; jj < 12; ++jj) acc[i][jj] += a[i] * wv_[jj];
    }
#pragma unroll
    for (int i = 0; i < 4; ++i) {
      int tok = tg * 4 + i;
      size_t basep = (size_t)(t0 + tok) * 448 + on * 12;
#pragma unroll
      for (int jj = 0; jj < 12; ++jj)
        out[basep + jj] = acc[i][jj] + conv_b[on * 12 + jj];
    }
  }
  // ---- LN1 + one GEMM: 4 passes of 16 tokens; arithmetic identical ----
  int tt = tid >> 4, part = tid & 15;
  float* dst = (type == 0) ? qo : (type == 1) ? ko : vo;
#pragma unroll 1
  for (int pass = 0; pass < 4; ++pass) {
    int tokL = pass * 16 + tt;
    int t = t0 + tokL;
    float sclv = scl[tokL];
    float e0 = A[part * 4 + 0][tokL] * sclv;
    float e1 = A[part * 4 + 1][tokL] * sclv;
    float e2 = A[part * 4 + 2][tokL] * sclv;
    float e3 = A[part * 4 + 3][tokL] * sclv;
    float mean = red16(e0 + e1 + e2 + e3) * 0.015625f;
    float d0 = e0 - mean, d1 = e1 - mean, d2 = e2 - mean, d3 = e3 - mean;
    float var = red16(d0 * d0 + d1 * d1 + d2 * d2 + d3 * d3) * 0.015625f;
    float rs = rsqrtf(var + 1e-5f);
    f4 g4 = *(const f4*)(g1 + part * 4);
    f4 b4 = *(const f4*)(b1 + part * 4);
    f4 hh;
    hh.x = d0 * rs * g4.x + b4.x; hh.y = d1 * rs * g4.y + b4.y;
    hh.z = d2 * rs * g4.z + b4.z; hh.w = d3 * rs * g4.w + b4.w;
    *(f4*)&hinS[tt][part * 4] = hh;
    __syncthreads();
    float a0 = 0, a1 = 0, a2 = 0, a3 = 0;
    for (int d = 0; d < 64; ++d) {
      float hd = hinS[tt][d];
      f4 w4 = *(const f4*)&wS[d * 64 + part * 4];
      a0 += hd * w4.x; a1 += hd * w4.y; a2 += hd * w4.z; a3 += hd * w4.w;
    }
    f4 r = {a0, a1, a2, a3};
    *(f4*)(dst + (size_t)t * 64 + part * 4) = r;
    __syncthreads();
  }
}

// ===== classic MHSA: bf16 MFMA flash attention (b128-V, exp2, permlane swap) =====
__global__ __launch_bounds__(256) void attn_kernel(const float* __restrict__ qg,
    const float* __restrict__ kg, const float* __restrict__ vg, float* __restrict__ ao) {
  __shared__ __align__(16) unsigned short Klds[Ln][8];    // 16 KB bf16 (pre-scaled)
  __shared__ __align__(16) unsigned short Vt[10][1032];   // 20.2 KB bf16, d-major (+pad)
  __shared__ __align__(16) unsigned short Qlds[128][8];   // 2 KB bf16
  int bh = blockIdx.x;
  int b = bh >> 3, hh = bh & 7;
  int tid = threadIdx.x;
  int qbase = (blockIdx.y << 7);    // 128 queries per block
  const float* kb = kg + (size_t)(b * Ln) * 64 + hh * 8;
  const float* vb = vg + (size_t)(b * Ln) * 64 + hh * 8;
  const float* qb = qg + (size_t)(b * Ln + qbase) * 64 + hh * 8;
  const float SC = 0.51006944f;     // (1/sqrt(8)) * log2(e), folded into K
#pragma unroll
  for (int p = 0; p < 8; ++p) {
    int e4 = p * 256 + tid;         // 0..2047
    int j = e4 >> 1, part = e4 & 1;
    f4 kv = *(const f4*)(kb + (size_t)j * 64 + part * 4);
    *(uint2*)&Klds[j][part * 4] =
        make_uint2(pk_bf16(kv.x * SC, kv.y * SC), pk_bf16(kv.z * SC, kv.w * SC));
    f4 vv = *(const f4*)(vb + (size_t)j * 64 + part * 4);
    unsigned int u01 = pk_bf16(vv.x, vv.y), u23 = pk_bf16(vv.z, vv.w);
    int d0 = part * 4;
    Vt[d0 + 0][j] = (unsigned short)u01;
    Vt[d0 + 1][j] = (unsigned short)(u01 >> 16);
    Vt[d0 + 2][j] = (unsigned short)u23;
    Vt[d0 + 3][j] = (unsigned short)(u23 >> 16);
  }
#pragma unroll
  for (int p = 0; p < 4; ++p) {
    int j = p * 256 + tid;
    Vt[8][j] = 0x3F80;              // ones row (denominator)
    Vt[9][j] = 0;                   // zero row (clamp target)
  }
  {
    int j = tid >> 1, part = tid & 1;
    f4 qv = *(const f4*)(qb + (size_t)j * 64 + part * 4);
    *(uint2*)&Qlds[j][part * 4] = make_uint2(pk_bf16(qv.x, qv.y), pk_bf16(qv.z, qv.w));
  }
  __syncthreads();

  int l = tid & 63, w = tid >> 6;
  int lq = l & 31;
  bool lo = l < 32;
  const short8 zero8 = {0, 0, 0, 0, 0, 0, 0, 0};
  short8 qf = *(const short8*)&Qlds[w * 32 + lq][0];
  qf = lo ? qf : zero8;
  int d = lq;
  int dc = d > 9 ? 9 : d;
  int vrow0 = (l >> 5) * 8;
  f32x16 acc = {};
  const f32x16 fz = {};
  for (int t = 0; t < 32; ++t) {
    short8 kf = *(const short8*)&Klds[t * 32 + lq][0];
    kf = lo ? kf : zero8;
    f32x16 s = __builtin_amdgcn_mfma_f32_32x32x16_bf16(kf, qf, fz, 0, 0, 0);
    float p[16];
#pragma unroll
    for (int r = 0; r < 16; ++r) p[r] = fast_exp2(s[r]);   // K pre-scaled: p = 2^s
    unsigned int c0 = pk_bf16(p[0], p[1]),  c1 = pk_bf16(p[2], p[3]);
    unsigned int c2 = pk_bf16(p[4], p[5]),  c3 = pk_bf16(p[6], p[7]);
    unsigned int c4 = pk_bf16(p[8], p[9]),  c5 = pk_bf16(p[10], p[11]);
    unsigned int c6 = pk_bf16(p[12], p[13]), c7 = pk_bf16(p[14], p[15]);
    // cross-half exchange via permlane32_swap: X=[a.lo|b.lo], Y=[a.hi|b.hi]
    unsigned int x0 = c0, y0 = c2;
    asm("v_permlane32_swap_b32 %0, %1" : "+v"(x0), "+v"(y0));
    unsigned int x1 = c1, y1 = c3;
    asm("v_permlane32_swap_b32 %0, %1" : "+v"(x1), "+v"(y1));
    unsigned int x4 = c4, y4 = c6;
    asm("v_permlane32_swap_b32 %0, %1" : "+v"(x4), "+v"(y4));
    unsigned int x5 = c5, y5 = c7;
    asm("v_permlane32_swap_b32 %0, %1" : "+v"(x5), "+v"(y5));
    union { u32x4 u; short8 s8; } B0, B1;
    B0.u = (u32x4){x0, x1, y0, y1};   // lo:{c0,c1,pc0,pc1} hi:{pc2,pc3,c2,c3}
    B1.u = (u32x4){x4, x5, y4, y5};   // lo:{c4,c5,pc4,pc5} hi:{pc6,pc7,c6,c7}
    int jb = t * 32 + vrow0;
    short8 av0 = *(const short8*)&Vt[dc][jb];        // ds_read_b128 (aligned)
    short8 av1 = *(const short8*)&Vt[dc][jb + 16];   // ds_read_b128
    acc = __builtin_amdgcn_mfma_f32_32x32x16_bf16(av0, B0.s8, acc, 0, 0, 0);
    acc = __builtin_amdgcn_mfma_f32_32x32x16_bf16(av1, B1.s8, acc, 0, 0, 0);
  }
  float ssum = __shfl(acc[4], lq);
  float inv = 1.0f / ssum;
  f4 o = {acc[0] * inv, acc[1] * inv, acc[2] * inv, acc[3] * inv};
  float* dst = ao + (size_t)(b * Ln + qbase + w * 32 + lq) * 64 + hh * 8 + (lo ? 0 : 4);
  *(f4*)dst = o;
}

// ========= out-proj residual + LN2 + normalize (st); woT staged in LDS =========
__global__ __launch_bounds__(256) void proj_st_kernel(float* __restrict__ t64st,
    const float* __restrict__ ao, const float* __restrict__ woT, const float* __restrict__ bo,
    const float* __restrict__ g2, const float* __restrict__ b2, const float* __restrict__ iscale,
    float* __restrict__ hB) {
  __shared__ float woS[4096];   // 16 KB
  __shared__ float aos[16][68]; // 68-pad: conflict-free tt-group reads
  int tid = threadIdx.x;
#pragma unroll
  for (int p = 0; p < 16; ++p) {
    int idx = p * 256 + tid;
    woS[idx] = woT[idx];
  }
  int t0 = blockIdx.x << 4;
  int tt = tid >> 4, part = tid & 15;
  int t = t0 + tt;
  *(f4*)&aos[tt][part * 4] = *(const f4*)(ao + (size_t)t * 64 + part * 4);
  __syncthreads();
  f4 acc;
  acc.x = bo[part * 4 + 0]; acc.y = bo[part * 4 + 1];
  acc.z = bo[part * 4 + 2]; acc.w = bo[part * 4 + 3];
  for (int d = 0; d < 64; ++d) {
    float ad = aos[tt][d];
    f4 w4 = *(const f4*)&woS[d * 64 + part * 4];
    acc.x += ad * w4.x; acc.y += ad * w4.y; acc.z += ad * w4.z; acc.w += ad * w4.w;
  }
  f4 tv = *(const f4*)(t64st + (size_t)t * 64 + part * 4);
  f4 hv = {tv.x + acc.x, tv.y + acc.y, tv.z + acc.z, tv.w + acc.w};
  *(f4*)(hB + (size_t)t * 64 + part * 4) = hv;
  float mean = red16(hv.x + hv.y + hv.z + hv.w) * 0.015625f;
  float d0 = hv.x - mean, d1 = hv.y - mean, d2 = hv.z - mean, d3 = hv.w - mean;
  float var = red16(d0 * d0 + d1 * d1 + d2 * d2 + d3 * d3) * 0.015625f;
  float rs = rsqrtf(var + 1e-5f);
  f4 g4 = *(const f4*)(g2 + part * 4);
  f4 b4 = *(const f4*)(b2 + part * 4);
  f4 is4 = *(const f4*)(iscale + part * 4);
  float x0 = (d0 * rs * g4.x + b4.x) * is4.x;
  float x1 = (d1 * rs * g4.y + b4.y) * is4.y;
  float x2 = (d2 * rs * g4.z + b4.z) * is4.z;
  float x3 = (d3 * rs * g4.w + b4.w) * is4.w;
  float nrm = sqrtf(red16(x0 * x0 + x1 * x1 + x2 * x2 + x3 * x3));
  float rn = 1.0f / (nrm + EPSn);
  f4 stv = {x0 * rn, x1 * rn, x2 * rn, x3 * rn};
  *(f4*)(t64st + (size_t)t * 64 + part * 4) = stv;
}

// ======== quantum: psi_out = st @ U_total^T as fp32 LDS GEMM + epilogue ========
__global__ __launch_bounds__(256) void quantum_kernel(const float* __restrict__ st,
    const float* __restrict__ ut,
    const float* __restrict__ qproj_w, const float* __restrict__ qproj_b,
    const float* __restrict__ kproj_w, const float* __restrict__ kproj_b,
    const float* __restrict__ qkg, const float* __restrict__ qkb,
    float* __restrict__ qvb, float* __restrict__ kvb, float* __restrict__ v64) {
  __shared__ float smem[12288];     // sts[4096] | ure[4096] | uim[4096]; plds aliases front
  int tid = threadIdx.x;
  int branch = blockIdx.y;
  int t0 = blockIdx.x << 6;         // 64 tokens/block
  const float* ub = ut + (size_t)branch * 8192;
#pragma unroll
  for (int p = 0; p < 16; ++p) {
    int idx = p * 256 + tid;        // 0..4095
    smem[idx] = st[(size_t)t0 * 64 + idx];
    smem[4096 + idx] = ub[idx];
    smem[8192 + idx] = ub[4096 + idx];
  }
  __syncthreads();
  int o = tid & 63, tg = tid >> 6;
  float accre[16], accim[16];
#pragma unroll
  for (int i = 0; i < 16; ++i) { accre[i] = 0.f; accim[i] = 0.f; }
  for (int k4 = 0; k4 < 16; ++k4) {
    float ur[4], ui[4];
#pragma unroll
    for (int j = 0; j < 4; ++j) {
      ur[j] = smem[4096 + (k4 * 4 + j) * 64 + o];   // stride-1 lanes: conflict-free
      ui[j] = smem[8192 + (k4 * 4 + j) * 64 + o];
    }
#pragma unroll
    for (int tt = 0; tt < 16; ++tt) {
      f4 a = *(const f4*)&smem[(tg * 16 + tt) * 64 + k4 * 4];  // broadcast
      accre[tt] += a.x * ur[0] + a.y * ur[1] + a.z * ur[2] + a.w * ur[3];
      accim[tt] += a.x * ui[0] + a.y * ui[1] + a.z * ui[2] + a.w * ui[3];
    }
  }
  __syncthreads();                  // everyone done reading sts/U
#pragma unroll
  for (int tt = 0; tt < 16; ++tt) {
    int t = tg * 16 + tt;
    smem[t * 65 + o] = accre[tt] * accre[tt] + accim[tt] * accim[tt];  // plds (65-pad)
  }
  __syncthreads();
  // ---- remap epilogue: thread (token, quarter s) ----
  int s = tid & 3;
  int tokL = tid >> 2;              // 0..63
  int token = t0 + tokL;
  bool bit1 = (s & 2) != 0;
  bool bit0 = (s & 1) != 0;
  float p[16];
#pragma unroll
  for (int i = 0; i < 16; ++i) p[i] = smem[tokL * 65 + s * 16 + i];
  float lsum = 0.f;
#pragma unroll
  for (int i = 0; i < 16; ++i) lsum += p[i];
  if (branch == 2) {
    float tot = lsum;
    tot += __shfl_xor(tot, 1);
    tot += __shfl_xor(tot, 2);
    float rn = 1.0f / (tot + EPSn);
    float* dst = v64 + (size_t)token * 64 + s * 16;
#pragma unroll
    for (int i = 0; i < 16; i += 4) {
      f4 o4 = {p[i] * rn, p[i + 1] * rn, p[i + 2] * rn, p[i + 3] * rn};
      *(f4*)(dst + i) = o4;
    }
  } else {
    float lz[4] = {0.f, 0.f, 0.f, 0.f};
#pragma unroll
    for (int i = 0; i < 16; ++i) {
      lz[0] += (i & 8) ? -p[i] : p[i];
      lz[1] += (i & 4) ? -p[i] : p[i];
      lz[2] += (i & 2) ? -p[i] : p[i];
      lz[3] += (i & 1) ? -p[i] : p[i];
    }
    float z[6];
    float u0 = bit1 ? -lsum : lsum;
    u0 += __shfl_xor(u0, 1); u0 += __shfl_xor(u0, 2); z[0] = u0;
    float u1 = bit0 ? -lsum : lsum;
    u1 += __shfl_xor(u1, 1); u1 += __shfl_xor(u1, 2); z[1] = u1;
#pragma unroll
    for (int q = 0; q < 4; ++q) {
      float v = lz[q];
      v += __shfl_xor(v, 1); v += __shfl_xor(v, 2);
      z[2 + q] = v;
    }
    const float* pw = branch == 0 ? qproj_w : kproj_w;
    const float* pb = branch == 0 ? qproj_b : kproj_b;
    float pr4[4];
#pragma unroll
    for (int jj = 0; jj < 4; ++jj) {
      float a = pb[jj];
#pragma unroll
      for (int qq = 0; qq < 6; ++qq) a += z[qq] * pw[jj * 6 + qq];
      pr4[jj] = a;
    }
    float mean = (pr4[0] + pr4[1] + pr4[2] + pr4[3]) * 0.25f;
    float var = 0.f;
#pragma unroll
    for (int jj = 0; jj < 4; ++jj) { float dd = pr4[jj] - mean; var += dd * dd; }
    var *= 0.25f;
    float rs = rsqrtf(var + 1e-5f);
    if (s == 0) {
      f4 o4;
      o4.x = (pr4[0] - mean) * rs * qkg[0] + qkb[0];
      o4.y = (pr4[1] - mean) * rs * qkg[1] + qkb[1];
      o4.z = (pr4[2] - mean) * rs * qkg[2] + qkb[2];
      o4.w = (pr4[3] - mean) * rs * qkg[3] + qkb[3];
      *(f4*)((branch == 0 ? qvb : kvb) + (size_t)token * 4) = o4;
    }
  }
}

// ==== RBF kernel attention: bf16 MFMA flash (transposed V, exp2-folded) ====
// Flat 256-block grid, XCD-aligned decode: qb = i>>5, b = (i&31)>>1, kc = i&1.
// 32==0 mod 8 => all 8 q-copies of a (b,kc) v64/kvb slice land on one XCD.
__global__ __launch_bounds__(256) void rbf_kernel(const float* __restrict__ qvb,
    const float* __restrict__ kvb, const float* __restrict__ v64,
    const float* __restrict__ raw_tau, float* __restrict__ pacc, float* __restrict__ pasum) {
  __shared__ __align__(16) unsigned short Vt[64][520];     // 65 KB bf16, d-major (+pad)
  __shared__ __align__(16) unsigned short kvbs[512][8];    // 8 KB bf16 (pre-scaled, 4+4 zero)
  __shared__ float kks[512];                               // (k.k)/tau * log2e
  int tid = threadIdx.x;
  int i = blockIdx.x;
  int qb = i >> 5;                   // 0..7  (q-subblock within batch)
  int pair = i & 31;
  int b = pair >> 1;                 // 0..15
  int kc = pair & 1;                 // key chunk (512 each)
  int q0 = ((b << 3) + qb) << 7;     // 128 queries/block (global token index)
  float tau = log1pf(__expf(raw_tau[0]));
  const float L2E = 1.4426950408889634f;
  float sck = 2.0f * L2E / tau;      // fold into staged k: s' = (q.k)*sck
  int kbase = b * Ln + (kc << 9);
#pragma unroll
  for (int p = 0; p < 2; ++p) {
    int j = p * 256 + tid;
    f4 kv4 = *(const f4*)(kvb + (size_t)(kbase + j) * 4);
    kks[j] = (kv4.x * kv4.x + kv4.y * kv4.y + kv4.z * kv4.z + kv4.w * kv4.w) * (L2E / tau);
    *(uint4*)&kvbs[j][0] =
        make_uint4(pk_bf16(kv4.x * sck, kv4.y * sck), pk_bf16(kv4.z * sck, kv4.w * sck), 0u, 0u);
  }
#pragma unroll
  for (int it = 0; it < 32; ++it) {
    int idx = it * 256 + tid;        // f4 index over 512*16
    int row = idx >> 4, c4 = idx & 15;
    f4 vv = *(const f4*)(v64 + (size_t)(kbase + row) * 64 + c4 * 4);
    unsigned int u01 = pk_bf16(vv.x, vv.y), u23 = pk_bf16(vv.z, vv.w);
    int d0 = c4 * 4;
    Vt[d0 + 0][row] = (unsigned short)u01;
    Vt[d0 + 1][row] = (unsigned short)(u01 >> 16);
    Vt[d0 + 2][row] = (unsigned short)u23;
    Vt[d0 + 3][row] = (unsigned short)(u23 >> 16);
  }
  __syncthreads();

  int l = tid & 63, w = tid >> 6;
  int lq = l & 31;
  bool lo = l < 32;
  bool hi = !lo;
  const short8 zero8 = {0, 0, 0, 0, 0, 0, 0, 0};
  int qtok = q0 + w * 32 + lq;
  f4 qv4 = *(const f4*)(qvb + (size_t)qtok * 4);
  union { u32x4 u; short8 s8; } Qf;
  Qf.u = (u32x4){pk_bf16(qv4.x, qv4.y), pk_bf16(qv4.z, qv4.w), 0u, 0u};
  short8 qf = lo ? Qf.s8 : zero8;
  int vrow0 = (l >> 5) * 8;
  int dbase = hi ? 4 : 0;
  f32x16 acc0 = {}, acc1 = {};
  const f32x16 fz = {};
  float dsum = 0.f;
  for (int t = 0; t < 16; ++t) {     // 16 tiles x 32 keys
    short8 kf = lo ? *(const short8*)&kvbs[t * 32 + lq][0] : zero8;
    f32x16 s = __builtin_amdgcn_mfma_f32_32x32x16_bf16(kf, qf, fz, 0, 0, 0);
    int rowbase = t * 32 + dbase;
    float p[16];
#pragma unroll
    for (int r = 0; r < 16; ++r) {
      float kkv = kks[rowbase + (r & 3) + 8 * (r >> 2)];
      p[r] = fast_exp2(s[r] - kkv);
      dsum += p[r];
    }
    unsigned int c0 = pk_bf16(p[0], p[1]),  c1 = pk_bf16(p[2], p[3]);
    unsigned int c2 = pk_bf16(p[4], p[5]),  c3 = pk_bf16(p[6], p[7]);
    unsigned int c4 = pk_bf16(p[8], p[9]),  c5 = pk_bf16(p[10], p[11]);
    unsigned int c6 = pk_bf16(p[12], p[13]), c7 = pk_bf16(p[14], p[15]);
    unsigned int x0 = c0, y0 = c2;
    asm("v_permlane32_swap_b32 %0, %1" : "+v"(x0), "+v"(y0));
    unsigned int x1 = c1, y1 = c3;
    asm("v_permlane32_swap_b32 %0, %1" : "+v"(x1), "+v"(y1));
    unsigned int x4 = c4, y4 = c6;
    asm("v_permlane32_swap_b32 %0, %1" : "+v"(x4), "+v"(y4));
    unsigned int x5 = c5, y5 = c7;
    asm("v_permlane32_swap_b32 %0, %1" : "+v"(x5), "+v"(y5));
    union { u32x4 u; short8 s8; } B0, B1;
    B0.u = (u32x4){x0, x1, y0, y1};
    B1.u = (u32x4){x4, x5, y4, y5};
    int jb = t * 32 + vrow0;
    short8 a00 = *(const short8*)&Vt[lq][jb];          // ds_read_b128
    short8 a10 = *(const short8*)&Vt[32 + lq][jb];
    short8 a01 = *(const short8*)&Vt[lq][jb + 16];
    short8 a11 = *(const short8*)&Vt[32 + lq][jb + 16];
    acc0 = __builtin_amdgcn_mfma_f32_32x32x16_bf16(a00, B0.s8, acc0, 0, 0, 0);
    acc1 = __builtin_amdgcn_mfma_f32_32x32x16_bf16(a10, B0.s8, acc1, 0, 0, 0);
    acc0 = __builtin_amdgcn_mfma_f32_32x32x16_bf16(a01, B1.s8, acc0, 0, 0, 0);
    acc1 = __builtin_amdgcn_mfma_f32_32x32x16_bf16(a11, B1.s8, acc1, 0, 0, 0);
  }
  float dtot = dsum + __shfl_xor(dsum, 32);
  if (lo) pasum[(kc << 14) + qtok] = dtot;
  float* pa = pacc + (size_t)kc * 1048576 + (size_t)qtok * 64;
#pragma unroll
  for (int r = 0; r < 16; ++r) {
    int dd = (r & 3) + 8 * (r >> 2) + dbase;
    pa[dd] = acc0[r];
    pa[32 + dd] = acc1[r];
  }
}

// == M0+M1+M2 fused: h += rbf; LN3; hid = gelu(.@w1); out = h + hid@w2 + b2 ==
__global__ __launch_bounds__(256) void m0m1m2_kernel(const float* __restrict__ hB,
    const float* __restrict__ pacc, const float* __restrict__ pasum,
    const float* __restrict__ g3, const float* __restrict__ b3,
    const float* __restrict__ w1p, const float* __restrict__ b1v,
    const float* __restrict__ w2p, const float* __restrict__ b2v,
    float* __restrict__ out) {
  __shared__ float hS[16][64];      // 4 KB: updated h (residual source)
  __shared__ float hmS[16][64];     // 4 KB: LN3 output
  __shared__ float hidS[16][256];   // 16 KB: gelu hidden
  int tid = threadIdx.x;
  int t0 = blockIdx.x << 4;
  {
    int tt = tid >> 4, part = tid & 15;
    int t = t0 + tt;
    f4 hv = *(const f4*)(hB + (size_t)t * 64 + part * 4);
    f4 p0 = *(const f4*)(pacc + (size_t)t * 64 + part * 4);
    f4 p1 = *(const f4*)(pacc + 1048576 + (size_t)t * 64 + part * 4);
    float rden = 1.0f / (pasum[t] + pasum[16384 + t] + EPSn);
    hv.x += (p0.x + p1.x) * rden; hv.y += (p0.y + p1.y) * rden;
    hv.z += (p0.z + p1.z) * rden; hv.w += (p0.w + p1.w) * rden;
    *(f4*)&hS[tt][part * 4] = hv;
    float mean = red16(hv.x + hv.y + hv.z + hv.w) * 0.015625f;
    float d0 = hv.x - mean, d1 = hv.y - mean, d2 = hv.z - mean, d3 = hv.w - mean;
    float var = red16(d0 * d0 + d1 * d1 + d2 * d2 + d3 * d3) * 0.015625f;
    float rs = rsqrtf(var + 1e-5f);
    f4 g4 = *(const f4*)(g3 + part * 4);
    f4 b4 = *(const f4*)(b3 + part * 4);
    f4 o4 = {d0 * rs * g4.x + b4.x, d1 * rs * g4.y + b4.y,
             d2 * rs * g4.z + b4.z, d3 * rs * g4.w + b4.w};
    *(f4*)&hmS[tt][part * 4] = o4;
  }
  __syncthreads();
  // ---- M1: u = tid computes hid[tok][u] for all 16 tokens ----
  {
    int u = tid;
    float wrow[64];
#pragma unroll
    for (int d4 = 0; d4 < 16; ++d4) {
      f4 w4 = *(const f4*)(w1p + d4 * 1024 + u * 4);   // coalesced
      wrow[d4 * 4] = w4.x; wrow[d4 * 4 + 1] = w4.y;
      wrow[d4 * 4 + 2] = w4.z; wrow[d4 * 4 + 3] = w4.w;
    }
    float bias = b1v[u];
    for (int tok = 0; tok < 16; ++tok) {
      const float* hr = hmS[tok];
      float a0 = 0.f, a1 = 0.f, a2 = 0.f, a3 = 0.f;
#pragma unroll
      for (int d = 0; d < 64; d += 4) {
        a0 += hr[d] * wrow[d];
        a1 += hr[d + 1] * wrow[d + 1];
        a2 += hr[d + 2] * wrow[d + 2];
        a3 += hr[d + 3] * wrow[d + 3];
      }
      float a = bias + ((a0 + a1) + (a2 + a3));
      float tz = 0.7978845608028654f * (a + 0.044715f * a * a * a);
      float e = __expf(2.0f * tz);
      float th = 1.0f - 2.0f / (e + 1.0f);
      hidS[tok][u] = 0.5f * a * (1.0f + th);
    }
  }
  __syncthreads();
  // ---- M2: lane owns out col o; 4 token-groups of 4 ----
  int o = tid & 63, tg = tid >> 6;
  f4 acc[4];
#pragma unroll
  for (int tt = 0; tt < 4; ++tt) acc[tt] = {0.f, 0.f, 0.f, 0.f};
#pragma unroll 4
  for (int u4 = 0; u4 < 64; ++u4) {
    f4 wv = *(const f4*)(w2p + u4 * 256 + o * 4);   // coalesced 1KB/wave, L2-hot
#pragma unroll
    for (int tt = 0; tt < 4; ++tt) {
      f4 hv = *(const f4*)&hidS[tg * 4 + tt][u4 * 4];   // broadcast (same addr per wave)
      acc[tt].x += hv.x * wv.x; acc[tt].y += hv.y * wv.y;
      acc[tt].z += hv.z * wv.z; acc[tt].w += hv.w * wv.w;
    }
  }
  float bb = b2v[o];
#pragma unroll
  for (int tt = 0; tt < 4; ++tt) {
    int tok = tg * 4 + tt;
    float r = bb + ((acc[tt].x + acc[tt].y) + (acc[tt].z + acc[tt].w));
    out[(size_t)(t0 + tok) * 448 + 384 + o] = hS[tok][o] + r;
  }
}

// ===================== host =====================
extern "C" void kernel_launch(void* const* d_in, const int* in_sizes, int n_in,
                              void* d_out, int out_size, void* d_ws, size_t ws_size,
                              hipStream_t stream) {
  (void)in_sizes; (void)n_in; (void)out_size; (void)ws_size;
  const float* x       = (const float*)d_in[0];
  const float* conv_w  = (const float*)d_in[1];
  const float* conv_b  = (const float*)d_in[2];
  const float* ln1_g   = (const float*)d_in[3];
  const float* ln1_b   = (const float*)d_in[4];
  const float* wq      = (const float*)d_in[5];
  const float* wk      = (const float*)d_in[6];
  const float* wv      = (const float*)d_in[7];
  const float* wo      = (const float*)d_in[8];
  const float* bo      = (const float*)d_in[9];
  const float* ln2_g   = (const float*)d_in[10];
  const float* ln2_b   = (const float*)d_in[11];
  const float* enc_w   = (const float*)d_in[12];
  const float* q_w     = (const float*)d_in[13];
  const float* k_w     = (const float*)d_in[14];
  const float* v_w     = (const float*)d_in[15];
  const float* mq_w    = (const float*)d_in[16];
  const float* mk_w    = (const float*)d_in[17];
  const float* mv_w    = (const float*)d_in[18];
  const float* qproj_w = (const float*)d_in[19];
  const float* qproj_b = (const float*)d_in[20];
  const float* kproj_w = (const float*)d_in[21];
  const float* kproj_b = (const float*)d_in[22];
  const float* qkln_g  = (const float*)d_in[23];
  const float* qkln_b  = (const float*)d_in[24];
  const float* raw_tau = (const float*)d_in[25];
  const float* iscale  = (const float*)d_in[26];
  const float* ln3_g   = (const float*)d_in[27];
  const float* ln3_b   = (const float*)d_in[28];
  const float* mlp_w1  = (const float*)d_in[29];
  const float* mlp_b1  = (const float*)d_in[30];
  const float* mlp_w2  = (const float*)d_in[31];
  const float* mlp_b2  = (const float*)d_in[32];
  float* out = (float*)d_out;
  float* ws  = (float*)d_ws;

  prep_all_kernel<<<300, 256, 0, stream>>>(conv_w, wq, wk, wv, wo, mlp_w1, mlp_w2,
                                           enc_w, q_w, k_w, v_w, mq_w, mk_w, mv_w, ws);
  patchqkv_kernel<<<768, 256, 0, stream>>>(x, ws + OFF_TR, conv_b,
                                           ws + OFF_WQT, ws + OFF_WKT, ws + OFF_WVT,
                                           ln1_g, ln1_b, out, ws + OFF_T64,
                                           ws + OFF_Q, ws + OFF_K, ws + OFF_V);
  attn_kernel<<<dim3(128, 8), 256, 0, stream>>>(ws + OFF_Q, ws + OFF_K, ws + OFF_V, ws + OFF_AO);
  proj_st_kernel<<<1024, 256, 0, stream>>>(ws + OFF_T64, ws + OFF_AO, ws + OFF_WOT, bo,
                                           ln2_g, ln2_b, iscale, ws + OFF_H);
  quantum_kernel<<<dim3(256, 3), 256, 0, stream>>>(ws + OFF_T64, ws + OFF_UT,
                                                   qproj_w, qproj_b, kproj_w, kproj_b,
                                                   qkln_g, qkln_b,
                                                   ws + OFF_K, ws + OFF_K + 65536, ws + OFF_Q);
  rbf_kernel<<<256, 256, 0, stream>>>(ws + OFF_K, ws + OFF_K + 65536, ws + OFF_Q,
                                      raw_tau, ws + OFF_V, ws + OFF_K + 131072);
  m0m1m2_kernel<<<1024, 256, 0, stream>>>(ws + OFF_H, ws + OFF_V, ws + OFF_K + 131072,
                                          ln3_g, ln3_b, ws + OFF_W1P, mlp_b1,
                                          ws + OFF_W2P, mlp_b2, out);
}